// Round 2
// baseline (1902.692 us; speedup 1.0000x reference)
//
#include <hip/hip_runtime.h>
#include <math.h>

#define BB 256
#define SS 4096
#define FF 8
#define HH 32
#define TT 256              // timesteps per LDS tile
#define NT (SS/TT)          // 16 tiles
#define NTHREADS 512
#define NG (NTHREADS/HH)    // 16 chunk groups
#define CL (TT/NG)          // 16 timesteps per chunk
#define HP 36               // padded LDS row stride

#define L2E  1.4426950408889634f
#define LN2f 0.6931471805599453f

__device__ __forceinline__ float fexp2(float x){
#if __has_builtin(__builtin_amdgcn_exp2f)
    return __builtin_amdgcn_exp2f(x);
#else
    return exp2f(x);
#endif
}
__device__ __forceinline__ float flog2(float x){
#if __has_builtin(__builtin_amdgcn_logf)
    return __builtin_amdgcn_logf(x);
#else
    return log2f(x);
#endif
}
__device__ __forceinline__ float frcp(float x){
#if __has_builtin(__builtin_amdgcn_rcpf)
    return __builtin_amdgcn_rcpf(x);
#else
    return 1.0f/x;
#endif
}

// softplus(z) = max(z,0) + ln2*log2(1 + 2^(-|z|*log2e))
__device__ __forceinline__ float softplus_n(float z){
    const float t = fexp2(-fabsf(z) * L2E);
    return fmaxf(z, 0.f) + LN2f * flog2(1.f + t);
}
// sigmoid(z) = 1/(1 + 2^(-z*log2e))
__device__ __forceinline__ float sigmoid_n(float z){
    return frcp(1.f + fexp2(-z * L2E));
}

__global__ __launch_bounds__(NTHREADS, 2)
void forecast_fused(const float* __restrict__ x,
                    const float* __restrict__ Wemb, const float* __restrict__ bemb,
                    const float* __restrict__ Wd,   const float* __restrict__ bd,
                    const float* __restrict__ Alog,
                    const float* __restrict__ Wg,   const float* __restrict__ bg,
                    const float* __restrict__ gmma, const float* __restrict__ beta,
                    const float* __restrict__ W1,   const float* __restrict__ b1,
                    const float* __restrict__ W2,   const float* __restrict__ b2,
                    float* __restrict__ out)
{
    __shared__ float xs[TT * FF];          // staged x tile
    __shared__ float h0s[TT][HP];          // h (block input / output, in place)
    __shared__ float cfA[NG][HH];          // chunk-final prefix products
    __shared__ float cfX[NG][HH];          // chunk-final local states
    __shared__ float cin[NG][HH];          // chunk carry-ins

    const int tid = threadIdx.x;
    const int c   = tid & (HH - 1);        // channel
    const int g   = tid >> 5;              // chunk group
    const int b   = blockIdx.x;
    const int ts0 = g * CL;

    // weight columns in registers
    float we[FF], wd1[HH], wg1[HH], wd2[HH];
#pragma unroll
    for (int f = 0; f < FF; ++f) we[f] = Wemb[f * HH + c];
#pragma unroll
    for (int k = 0; k < HH; ++k) {
        wd1[k] = Wd[k * HH + c];
        wg1[k] = Wg[k * HH + c];
        wd2[k] = Wd[HH * HH + k * HH + c];
    }
    const float bec = bemb[c];
    const float bd1 = bd[c], bg1 = bg[c], bd2 = bd[HH + c];
    const float nA1 = -expf(Alog[c]) * L2E;      // exp(delta*-e^A) = 2^(delta*nA1)
    const float nA2 = -expf(Alog[HH + c]) * L2E;

    float s1v = 0.f, s2v = 0.f;            // running carries (lanes<32 of wave0)
    float prefA[CL], loc[CL], gt[CL];      // register-resident scan state

    for (int it = 0; it < NT; ++it) {
        // ---- X: stage x tile (512 x float4 = 2048 floats) ----
        const float4* xg = reinterpret_cast<const float4*>(x + ((size_t)b * SS + it * TT) * FF);
        reinterpret_cast<float4*>(xs)[tid] = xg[tid];
        __syncthreads();

        // ---- E: embed ----
#pragma unroll
        for (int r = 0; r < CL; ++r) {
            const int ts = ts0 + r;
            const float4 xv0 = *reinterpret_cast<const float4*>(&xs[ts * FF]);
            const float4 xv1 = *reinterpret_cast<const float4*>(&xs[ts * FF + 4]);
            float acc = bec;
            acc += xv0.x*we[0] + xv0.y*we[1] + xv0.z*we[2] + xv0.w*we[3];
            acc += xv1.x*we[4] + xv1.y*we[5] + xv1.z*we[6] + xv1.w*we[7];
            h0s[ts][c] = acc;
        }
        __syncthreads();

        // ---- D1 + A1: matvecs, pointwise, chunk-local scan in registers ----
        {
            float sp = 1.f, sl = 0.f;
#pragma unroll
            for (int r = 0; r < CL; ++r) {
                const int ts = ts0 + r;
                const float* hrow = &h0s[ts][0];
                float zd = bd1, zg = bg1;
#pragma unroll
                for (int k = 0; k < HH; k += 4) {
                    const float4 hv = *reinterpret_cast<const float4*>(hrow + k);
                    zd += hv.x*wd1[k] + hv.y*wd1[k+1] + hv.z*wd1[k+2] + hv.w*wd1[k+3];
                    zg += hv.x*wg1[k] + hv.y*wg1[k+1] + hv.z*wg1[k+2] + hv.w*wg1[k+3];
                }
                const float hc    = hrow[c];
                const float delta = softplus_n(zd);
                const float ab    = fexp2(delta * nA1);
                sl = ab * sl + delta * hc;
                sp *= ab;
                prefA[r] = sp;
                loc[r]   = sl;
                gt[r]    = sigmoid_n(zg);
            }
            cfA[g][c] = sp;
            cfX[g][c] = sl;
        }
        __syncthreads();

        // ---- B1: cross-chunk carry combine (one wave, batched reads) ----
        if (tid < HH) {
            float A[NG], X[NG];
#pragma unroll
            for (int ch = 0; ch < NG; ++ch) { A[ch] = cfA[ch][tid]; X[ch] = cfX[ch][tid]; }
            float cy = s1v;
#pragma unroll
            for (int ch = 0; ch < NG; ++ch) { cin[ch][tid] = cy; cy = A[ch] * cy + X[ch]; }
            s1v = cy;
        }
        __syncthreads();

        // ---- C1: fixup + residual gate: h1 = h0 + state*gate ----
        {
            const float ci = cin[g][c];
#pragma unroll
            for (int r = 0; r < CL; ++r) {
                const int ts = ts0 + r;
                const float st = loc[r] + prefA[r] * ci;
                h0s[ts][c] += st * gt[r];
            }
        }
        __syncthreads();

        // ---- D2 + A2: block-2 delta path + local scan ----
        {
            float sp = 1.f, sl = 0.f;
#pragma unroll
            for (int r = 0; r < CL; ++r) {
                const int ts = ts0 + r;
                const float* hrow = &h0s[ts][0];
                float zd = bd2;
#pragma unroll
                for (int k = 0; k < HH; k += 4) {
                    const float4 hv = *reinterpret_cast<const float4*>(hrow + k);
                    zd += hv.x*wd2[k] + hv.y*wd2[k+1] + hv.z*wd2[k+2] + hv.w*wd2[k+3];
                }
                const float hc    = hrow[c];
                const float delta = softplus_n(zd);
                const float ab    = fexp2(delta * nA2);
                sl = ab * sl + delta * hc;
                sp *= ab;
            }
            cfA[g][c] = sp;
            cfX[g][c] = sl;
        }
        __syncthreads();

        // ---- B2: carry only (block-2 states never materialized) ----
        if (tid < HH) {
            float cy = s2v;
#pragma unroll
            for (int ch = 0; ch < NG; ++ch) cy = cfA[ch][tid] * cy + cfX[ch][tid];
            s2v = cy;
        }
        // no barrier: next-iter E-barrier orders h0s/cf writes after B2
    }
    __syncthreads();

    // ---- head: gate2 on last token, residual, LN, GELU MLP -> scalar ----
    if (tid < HH) {
        float zg = bg[HH + tid];
#pragma unroll
        for (int k = 0; k < HH; ++k) zg += h0s[TT - 1][k] * Wg[HH * HH + k * HH + tid];
        const float gt2 = sigmoid_n(zg);
        const float h2  = h0s[TT - 1][tid] + s2v * gt2;

        float sum = h2;
#pragma unroll
        for (int m = 1; m < HH; m <<= 1) sum += __shfl_xor(sum, m);
        const float mu = sum * (1.0f / HH);
        const float d  = h2 - mu;
        float vs = d * d;
#pragma unroll
        for (int m = 1; m < HH; m <<= 1) vs += __shfl_xor(vs, m);
        const float rstd = rsqrtf(vs * (1.0f / HH) + 1e-5f);
        const float hn   = d * rstd * gmma[tid] + beta[tid];

        float z = b1[tid];
#pragma unroll
        for (int k = 0; k < HH; ++k) z += __shfl(hn, k) * W1[k * HH + tid];
        // gelu tanh-approx; tanh(t) = 1 - 2/(1+2^(2t*log2e))
        const float u  = 2.0f * L2E * 0.7978845608028654f * (z + 0.044715f * z * z * z);
        const float e  = fexp2(u);
        const float th = 1.f - 2.f * frcp(1.f + e);
        const float ge = 0.5f * z * (1.0f + th);
        float v = ge * W2[tid];
#pragma unroll
        for (int m = 1; m < HH; m <<= 1) v += __shfl_xor(v, m);
        if (tid == 0) out[b] = v + b2[0];
    }
}

extern "C" void kernel_launch(void* const* d_in, const int* in_sizes, int n_in,
                              void* d_out, int out_size, void* d_ws, size_t ws_size,
                              hipStream_t stream) {
    const float* x    = (const float*)d_in[0];
    const float* Wemb = (const float*)d_in[1];
    const float* bemb = (const float*)d_in[2];
    const float* Wd   = (const float*)d_in[3];
    const float* bd   = (const float*)d_in[4];
    const float* Alog = (const float*)d_in[5];
    const float* Wg   = (const float*)d_in[6];
    const float* bg   = (const float*)d_in[7];
    const float* gmma = (const float*)d_in[8];
    const float* beta = (const float*)d_in[9];
    const float* W1   = (const float*)d_in[10];
    const float* b1   = (const float*)d_in[11];
    const float* W2   = (const float*)d_in[12];
    const float* b2   = (const float*)d_in[13];
    float* out = (float*)d_out;

    forecast_fused<<<dim3(BB), dim3(NTHREADS), 0, stream>>>(
        x, Wemb, bemb, Wd, bd, Alog, Wg, bg, gmma, beta, W1, b1, W2, b2, out);
}

// Round 4
// 269.409 us; speedup vs baseline: 7.0625x; 7.0625x over previous
//
#include <hip/hip_runtime.h>
#include <math.h>

#define BB 256
#define SS 4096
#define FF 8
#define HH 32
#define TT 256              // timesteps per LDS tile
#define NT (SS/TT)          // 16 tiles
#define NTHREADS 512
#define NG (NTHREADS/HH)    // 16 chunk groups
#define CL (TT/NG)          // 16 timesteps per chunk
#define HP 36               // padded LDS row stride

#define L2E  1.4426950408889634f
#define LN2f 0.6931471805599453f

__device__ __forceinline__ float fexp2(float x){
#if __has_builtin(__builtin_amdgcn_exp2f)
    return __builtin_amdgcn_exp2f(x);
#else
    return exp2f(x);
#endif
}
__device__ __forceinline__ float flog2(float x){
#if __has_builtin(__builtin_amdgcn_logf)
    return __builtin_amdgcn_logf(x);
#else
    return log2f(x);
#endif
}
__device__ __forceinline__ float frcp(float x){
#if __has_builtin(__builtin_amdgcn_rcpf)
    return __builtin_amdgcn_rcpf(x);
#else
    return 1.0f/x;
#endif
}

// softplus(z) = max(z,0) + ln2*log2(1 + 2^(-|z|*log2e))
__device__ __forceinline__ float softplus_n(float z){
    const float t = fexp2(-fabsf(z) * L2E);
    return fmaxf(z, 0.f) + LN2f * flog2(1.f + t);
}
// sigmoid(z) = 1/(1 + 2^(-z*log2e))
__device__ __forceinline__ float sigmoid_n(float z){
    return frcp(1.f + fexp2(-z * L2E));
}

__global__ __launch_bounds__(NTHREADS)
void forecast_fused(const float* __restrict__ x,
                    const float* __restrict__ Wemb, const float* __restrict__ bemb,
                    const float* __restrict__ Wd,   const float* __restrict__ bd,
                    const float* __restrict__ Alog,
                    const float* __restrict__ Wg,   const float* __restrict__ bg,
                    const float* __restrict__ gmma, const float* __restrict__ beta,
                    const float* __restrict__ W1,   const float* __restrict__ b1,
                    const float* __restrict__ W2,   const float* __restrict__ b2,
                    float* __restrict__ out)
{
    __shared__ float xs[TT * FF];          // staged x tile                  8 KB
    __shared__ float h0s[TT][HP];          // h (in place)                  36.9 KB
    __shared__ float abS[TT][HP];          // prefix products               36.9 KB
    __shared__ float xiS[TT][HP];          // local scan states             36.9 KB
    __shared__ float gtS[TT][HP];          // gate (block 1)                36.9 KB
    __shared__ float cin[NG][HH];          // chunk carry-ins                2 KB

    const int tid = threadIdx.x;
    const int c   = tid & (HH - 1);        // channel
    const int g   = tid >> 5;              // chunk group
    const int b   = blockIdx.x;
    const int ts0 = g * CL;

    // weight columns in registers (per-lane column c)
    float we[FF], wd1[HH], wg1[HH], wd2[HH];
#pragma unroll
    for (int f = 0; f < FF; ++f) we[f] = Wemb[f * HH + c];
#pragma unroll
    for (int k = 0; k < HH; ++k) {
        wd1[k] = Wd[k * HH + c];
        wg1[k] = Wg[k * HH + c];
        wd2[k] = Wd[HH * HH + k * HH + c];
    }
    const float bec = bemb[c];
    const float bd1 = bd[c], bg1 = bg[c], bd2 = bd[HH + c];
    const float nA1 = -expf(Alog[c]) * L2E;      // exp(delta*-e^A) = 2^(delta*nA1)
    const float nA2 = -expf(Alog[HH + c]) * L2E;

    float s1v = 0.f, s2v = 0.f;            // running carries (lanes<32 of wave0)

    for (int it = 0; it < NT; ++it) {
        // ---- X: stage x tile (512 x float4 = 2048 floats) ----
        const float4* xg = reinterpret_cast<const float4*>(x + ((size_t)b * SS + it * TT) * FF);
        reinterpret_cast<float4*>(xs)[tid] = xg[tid];
        __syncthreads();

        // ---- E: embed ----
#pragma unroll
        for (int r = 0; r < CL; ++r) {
            const int ts = ts0 + r;
            const float4 xv0 = *reinterpret_cast<const float4*>(&xs[ts * FF]);
            const float4 xv1 = *reinterpret_cast<const float4*>(&xs[ts * FF + 4]);
            float acc = bec;
            acc += xv0.x*we[0] + xv0.y*we[1] + xv0.z*we[2] + xv0.w*we[3];
            acc += xv1.x*we[4] + xv1.y*we[5] + xv1.z*we[6] + xv1.w*we[7];
            h0s[ts][c] = acc;
        }
        __syncthreads();

        // ---- D1 (+fused local scan): matvecs, pointwise; scalars sp/sl carry
        //      the chunk-local scan; LDS gets prefix-product & local state ----
        {
            float sp = 1.f, sl = 0.f;
#pragma unroll
            for (int r = 0; r < CL; ++r) {
                const int ts = ts0 + r;
                const float* hrow = &h0s[ts][0];
                float zd = bd1, zg = bg1;
#pragma unroll
                for (int k = 0; k < HH; k += 4) {
                    const float4 hv = *reinterpret_cast<const float4*>(hrow + k);
                    zd += hv.x*wd1[k] + hv.y*wd1[k+1] + hv.z*wd1[k+2] + hv.w*wd1[k+3];
                    zg += hv.x*wg1[k] + hv.y*wg1[k+1] + hv.z*wg1[k+2] + hv.w*wg1[k+3];
                }
                const float hc    = hrow[c];
                const float delta = softplus_n(zd);
                const float ab    = fexp2(delta * nA1);
                sl = ab * sl + delta * hc;
                sp *= ab;
                abS[ts][c] = sp;
                xiS[ts][c] = sl;
                gtS[ts][c] = sigmoid_n(zg);
            }
        }
        __syncthreads();

        // ---- B1: cross-chunk carry combine (one wave; batched loads, short FMA chain) ----
        if (tid < HH) {
            float A[NG], X[NG];
#pragma unroll
            for (int ch = 0; ch < NG; ++ch) {
                A[ch] = abS[ch * CL + CL - 1][tid];
                X[ch] = xiS[ch * CL + CL - 1][tid];
            }
            float cy = s1v;
#pragma unroll
            for (int ch = 0; ch < NG; ++ch) { cin[ch][tid] = cy; cy = A[ch] * cy + X[ch]; }
            s1v = cy;
        }
        __syncthreads();

        // ---- C1: fixup + residual gate: h1 = h0 + (loc + pref*cin)*gate ----
        {
            const float ci = cin[g][c];
#pragma unroll
            for (int r = 0; r < CL; ++r) {
                const int ts = ts0 + r;
                const float st = xiS[ts][c] + abS[ts][c] * ci;
                h0s[ts][c] += st * gtS[ts][c];
            }
        }
        __syncthreads();

        // ---- D2 (+fused local scan): block-2 delta path ----
        {
            float sp = 1.f, sl = 0.f;
#pragma unroll
            for (int r = 0; r < CL; ++r) {
                const int ts = ts0 + r;
                const float* hrow = &h0s[ts][0];
                float zd = bd2;
#pragma unroll
                for (int k = 0; k < HH; k += 4) {
                    const float4 hv = *reinterpret_cast<const float4*>(hrow + k);
                    zd += hv.x*wd2[k] + hv.y*wd2[k+1] + hv.z*wd2[k+2] + hv.w*wd2[k+3];
                }
                const float hc    = hrow[c];
                const float delta = softplus_n(zd);
                const float ab    = fexp2(delta * nA2);
                sl = ab * sl + delta * hc;
                sp *= ab;
                abS[ts][c] = sp;
                xiS[ts][c] = sl;
            }
        }
        __syncthreads();

        // ---- B2: carry only (block-2 states never materialized) ----
        if (tid < HH) {
            float A[NG], X[NG];
#pragma unroll
            for (int ch = 0; ch < NG; ++ch) {
                A[ch] = abS[ch * CL + CL - 1][tid];
                X[ch] = xiS[ch * CL + CL - 1][tid];
            }
            float cy = s2v;
#pragma unroll
            for (int ch = 0; ch < NG; ++ch) cy = A[ch] * cy + X[ch];
            s2v = cy;
        }
        // no barrier needed: B2 reads abS/xiS which are next written in D1,
        // and two barriers (post-X, post-E) separate us from there.
    }
    __syncthreads();

    // ---- head: gate2 on last token, residual, LN, GELU MLP -> scalar ----
    if (tid < HH) {
        float zg = bg[HH + tid];
#pragma unroll
        for (int k = 0; k < HH; ++k) zg += h0s[TT - 1][k] * Wg[HH * HH + k * HH + tid];
        const float gt2 = sigmoid_n(zg);
        const float h2  = h0s[TT - 1][tid] + s2v * gt2;

        float sum = h2;
#pragma unroll
        for (int m = 1; m < HH; m <<= 1) sum += __shfl_xor(sum, m);
        const float mu = sum * (1.0f / HH);
        const float d  = h2 - mu;
        float vs = d * d;
#pragma unroll
        for (int m = 1; m < HH; m <<= 1) vs += __shfl_xor(vs, m);
        const float rstd = rsqrtf(vs * (1.0f / HH) + 1e-5f);
        const float hn   = d * rstd * gmma[tid] + beta[tid];

        float z = b1[tid];
#pragma unroll
        for (int k = 0; k < HH; ++k) z += __shfl(hn, k) * W1[k * HH + tid];
        // gelu tanh-approx; tanh(t) = 1 - 2/(1+2^(2t*log2e))
        const float u  = 2.0f * L2E * 0.7978845608028654f * (z + 0.044715f * z * z * z);
        const float e  = fexp2(u);
        const float th = 1.f - 2.f * frcp(1.f + e);
        const float ge = 0.5f * z * (1.0f + th);
        float v = ge * W2[tid];
#pragma unroll
        for (int m = 1; m < HH; m <<= 1) v += __shfl_xor(v, m);
        if (tid == 0) out[b] = v + b2[0];
    }
}

extern "C" void kernel_launch(void* const* d_in, const int* in_sizes, int n_in,
                              void* d_out, int out_size, void* d_ws, size_t ws_size,
                              hipStream_t stream) {
    const float* x    = (const float*)d_in[0];
    const float* Wemb = (const float*)d_in[1];
    const float* bemb = (const float*)d_in[2];
    const float* Wd   = (const float*)d_in[3];
    const float* bd   = (const float*)d_in[4];
    const float* Alog = (const float*)d_in[5];
    const float* Wg   = (const float*)d_in[6];
    const float* bg   = (const float*)d_in[7];
    const float* gmma = (const float*)d_in[8];
    const float* beta = (const float*)d_in[9];
    const float* W1   = (const float*)d_in[10];
    const float* b1   = (const float*)d_in[11];
    const float* W2   = (const float*)d_in[12];
    const float* b2   = (const float*)d_in[13];
    float* out = (float*)d_out;

    forecast_fused<<<dim3(BB), dim3(NTHREADS), 0, stream>>>(
        x, Wemb, bemb, Wd, bd, Alog, Wg, bg, gmma, beta, W1, b1, W2, b2, out);
}

// Round 5
// 223.383 us; speedup vs baseline: 8.5176x; 1.2060x over previous
//
#include <hip/hip_runtime.h>
#include <math.h>

#define BB 256
#define SS 4096
#define FF 8
#define HH 32
#define TT 128              // timesteps per LDS tile
#define NT (SS/TT)          // 32 tiles
#define NTHREADS 512
#define NG (NTHREADS/HH)    // 16 chunk groups
#define CL (TT/NG)          // 8 timesteps per chunk
#define HP 36               // padded LDS row stride

#define L2E  1.4426950408889634f
#define LN2f 0.6931471805599453f

__device__ __forceinline__ float fexp2(float x){
#if __has_builtin(__builtin_amdgcn_exp2f)
    return __builtin_amdgcn_exp2f(x);
#else
    return exp2f(x);
#endif
}
__device__ __forceinline__ float flog2(float x){
#if __has_builtin(__builtin_amdgcn_logf)
    return __builtin_amdgcn_logf(x);
#else
    return log2f(x);
#endif
}
__device__ __forceinline__ float frcp(float x){
#if __has_builtin(__builtin_amdgcn_rcpf)
    return __builtin_amdgcn_rcpf(x);
#else
    return 1.0f/x;
#endif
}

// softplus(z) = max(z,0) + ln2*log2(1 + 2^(-|z|*log2e))
__device__ __forceinline__ float softplus_n(float z){
    const float t = fexp2(-fabsf(z) * L2E);
    return fmaxf(z, 0.f) + LN2f * flog2(1.f + t);
}
// sigmoid(z) = 1/(1 + 2^(-z*log2e))
__device__ __forceinline__ float sigmoid_n(float z){
    return frcp(1.f + fexp2(-z * L2E));
}

__global__ __launch_bounds__(NTHREADS)
void forecast_fused(const float* __restrict__ x,
                    const float* __restrict__ Wemb, const float* __restrict__ bemb,
                    const float* __restrict__ Wd,   const float* __restrict__ bd,
                    const float* __restrict__ Alog,
                    const float* __restrict__ Wg,   const float* __restrict__ bg,
                    const float* __restrict__ gmma, const float* __restrict__ beta,
                    const float* __restrict__ W1,   const float* __restrict__ b1,
                    const float* __restrict__ W2,   const float* __restrict__ b2,
                    float* __restrict__ out)
{
    __shared__ float xs[TT * FF];          // staged x tile                 4 KB
    __shared__ float h1s[TT][HP];          // block-1 output rows          18.4 KB
    __shared__ float wdpS[FF][HH];         // Wemb@Wd1 composed             1 KB
    __shared__ float wgpS[FF][HH];         // Wemb@Wg1 composed             1 KB
    __shared__ float bdpS[HH], bgpS[HH];   // composed biases
    __shared__ float cfA[NG][HH];          // chunk-final prefix products   2 KB
    __shared__ float cfX[NG][HH];          // chunk-final local states      2 KB
    __shared__ float cin[NG][HH];          // chunk carry-ins               2 KB

    const int tid = threadIdx.x;
    const int c   = tid & (HH - 1);        // channel
    const int g   = tid >> 5;              // chunk group
    const int b   = blockIdx.x;
    const int ts0 = g * CL;

    // ---- one-time: compose block-1 weights through the embedding ----
    // zd1 = h0@Wd1+bd1 = x@(We@Wd1) + (be@Wd1+bd1); same for zg1.
    if (tid < FF * HH) {
        const int f = tid >> 5, cc = tid & 31;
        float accd = 0.f, accg = 0.f;
#pragma unroll
        for (int k = 0; k < HH; ++k) {
            const float w = Wemb[f * HH + k];
            accd += w * Wd[k * HH + cc];
            accg += w * Wg[k * HH + cc];
        }
        wdpS[f][cc] = accd;
        wgpS[f][cc] = accg;
    }
    if (tid < HH) {
        float ad = bd[tid], ag = bg[tid];
#pragma unroll
        for (int k = 0; k < HH; ++k) {
            ad += bemb[k] * Wd[k * HH + tid];
            ag += bemb[k] * Wg[k * HH + tid];
        }
        bdpS[tid] = ad; bgpS[tid] = ag;
    }
    __syncthreads();

    // per-lane register weights (column c)
    float we[FF], wd1p[FF], wg1p[FF], wd2[HH];
#pragma unroll
    for (int f = 0; f < FF; ++f) {
        we[f]   = Wemb[f * HH + c];
        wd1p[f] = wdpS[f][c];
        wg1p[f] = wgpS[f][c];
    }
#pragma unroll
    for (int k = 0; k < HH; ++k) wd2[k] = Wd[HH * HH + k * HH + c];
    const float bec  = bemb[c];
    const float bd1p = bdpS[c], bg1p = bgpS[c], bd2 = bd[HH + c];
    const float nA1 = -expf(Alog[c]) * L2E;
    const float nA2 = -expf(Alog[HH + c]) * L2E;

    float s1v = 0.f, s2v = 0.f;            // running carries (lanes<32 of wave0)

    for (int it = 0; it < NT; ++it) {
        // ---- X: stage x tile (512 x float2 = 1024 floats) ----
        const float2* xg2 = reinterpret_cast<const float2*>(x + ((size_t)b * SS + it * TT) * FF);
        reinterpret_cast<float2*>(xs)[tid] = xg2[tid];
        __syncthreads();

        // ---- D1: h0/zd1/zg1 straight from x (K=8); local scan in registers ----
        float prefA[CL], loc[CL], gtv[CL], h0r[CL];
        {
            float sp = 1.f, sl = 0.f;
#pragma unroll
            for (int r = 0; r < CL; ++r) {
                const int ts = ts0 + r;
                const float4 xv0 = *reinterpret_cast<const float4*>(&xs[ts * FF]);
                const float4 xv1 = *reinterpret_cast<const float4*>(&xs[ts * FF + 4]);
                float h0 = bec, zd = bd1p, zg = bg1p;
                h0 += xv0.x*we[0]   + xv0.y*we[1]   + xv0.z*we[2]   + xv0.w*we[3];
                h0 += xv1.x*we[4]   + xv1.y*we[5]   + xv1.z*we[6]   + xv1.w*we[7];
                zd += xv0.x*wd1p[0] + xv0.y*wd1p[1] + xv0.z*wd1p[2] + xv0.w*wd1p[3];
                zd += xv1.x*wd1p[4] + xv1.y*wd1p[5] + xv1.z*wd1p[6] + xv1.w*wd1p[7];
                zg += xv0.x*wg1p[0] + xv0.y*wg1p[1] + xv0.z*wg1p[2] + xv0.w*wg1p[3];
                zg += xv1.x*wg1p[4] + xv1.y*wg1p[5] + xv1.z*wg1p[6] + xv1.w*wg1p[7];
                const float delta = softplus_n(zd);
                const float ab    = fexp2(delta * nA1);
                sl = ab * sl + delta * h0;
                sp *= ab;
                prefA[r] = sp;
                loc[r]   = sl;
                gtv[r]   = sigmoid_n(zg);
                h0r[r]   = h0;
            }
            cfA[g][c] = sp;
            cfX[g][c] = sl;
        }
        __syncthreads();

        // ---- B1: cross-chunk carry combine (one wave) ----
        if (tid < HH) {
            float A[NG], X[NG];
#pragma unroll
            for (int ch = 0; ch < NG; ++ch) {
                A[ch] = cfA[ch][tid];
                X[ch] = cfX[ch][tid];
            }
            float cy = s1v;
#pragma unroll
            for (int ch = 0; ch < NG; ++ch) { cin[ch][tid] = cy; cy = A[ch] * cy + X[ch]; }
            s1v = cy;
        }
        __syncthreads();

        // ---- C1: fixup + residual gate, write h1 rows for D2 ----
        {
            const float ci = cin[g][c];
#pragma unroll
            for (int r = 0; r < CL; ++r) {
                const float st = loc[r] + prefA[r] * ci;
                h1s[ts0 + r][c] = h0r[r] + st * gtv[r];
            }
        }
        __syncthreads();

        // ---- D2: block-2 delta path (K=32 row reads) + local scan (scalars) ----
        {
            float sp = 1.f, sl = 0.f;
#pragma unroll
            for (int r = 0; r < CL; ++r) {
                const int ts = ts0 + r;
                const float* hrow = &h1s[ts][0];
                float zd = bd2;
#pragma unroll
                for (int k = 0; k < HH; k += 4) {
                    const float4 hv = *reinterpret_cast<const float4*>(hrow + k);
                    zd += hv.x*wd2[k] + hv.y*wd2[k+1] + hv.z*wd2[k+2] + hv.w*wd2[k+3];
                }
                const float hc    = hrow[c];
                const float delta = softplus_n(zd);
                const float ab    = fexp2(delta * nA2);
                sl = ab * sl + delta * hc;
                sp *= ab;
            }
            cfA[g][c] = sp;
            cfX[g][c] = sl;
        }
        __syncthreads();

        // ---- B2: carry only (block-2 states never materialized) ----
        if (tid < HH) {
            float A[NG], X[NG];
#pragma unroll
            for (int ch = 0; ch < NG; ++ch) {
                A[ch] = cfA[ch][tid];
                X[ch] = cfX[ch][tid];
            }
            float cy = s2v;
#pragma unroll
            for (int ch = 0; ch < NG; ++ch) cy = A[ch] * cy + X[ch];
            s2v = cy;
        }
        // no barrier: non-wave0 threads run ahead only into the next X-stage
        // (xs already consumed) and then wait at the post-X barrier, which
        // wave0 reaches only after finishing B2; cfA/cfX next written in D1
        // which is after that barrier.
    }
    __syncthreads();

    // ---- head: gate2 on last token, residual, LN, GELU MLP -> scalar ----
    if (tid < HH) {
        float zg = bg[HH + tid];
#pragma unroll
        for (int k = 0; k < HH; ++k) zg += h1s[TT - 1][k] * Wg[HH * HH + k * HH + tid];
        const float gt2 = sigmoid_n(zg);
        const float h2  = h1s[TT - 1][tid] + s2v * gt2;

        float sum = h2;
#pragma unroll
        for (int m = 1; m < HH; m <<= 1) sum += __shfl_xor(sum, m);
        const float mu = sum * (1.0f / HH);
        const float d  = h2 - mu;
        float vs = d * d;
#pragma unroll
        for (int m = 1; m < HH; m <<= 1) vs += __shfl_xor(vs, m);
        const float rstd = rsqrtf(vs * (1.0f / HH) + 1e-5f);
        const float hn   = d * rstd * gmma[tid] + beta[tid];

        float z = b1[tid];
#pragma unroll
        for (int k = 0; k < HH; ++k) z += __shfl(hn, k) * W1[k * HH + tid];
        // gelu tanh-approx; tanh(t) = 1 - 2/(1+2^(2t*log2e))
        const float u  = 2.0f * L2E * 0.7978845608028654f * (z + 0.044715f * z * z * z);
        const float e  = fexp2(u);
        const float th = 1.f - 2.f * frcp(1.f + e);
        const float ge = 0.5f * z * (1.0f + th);
        float v = ge * W2[tid];
#pragma unroll
        for (int m = 1; m < HH; m <<= 1) v += __shfl_xor(v, m);
        if (tid == 0) out[b] = v + b2[0];
    }
}

extern "C" void kernel_launch(void* const* d_in, const int* in_sizes, int n_in,
                              void* d_out, int out_size, void* d_ws, size_t ws_size,
                              hipStream_t stream) {
    const float* x    = (const float*)d_in[0];
    const float* Wemb = (const float*)d_in[1];
    const float* bemb = (const float*)d_in[2];
    const float* Wd   = (const float*)d_in[3];
    const float* bd   = (const float*)d_in[4];
    const float* Alog = (const float*)d_in[5];
    const float* Wg   = (const float*)d_in[6];
    const float* bg   = (const float*)d_in[7];
    const float* gmma = (const float*)d_in[8];
    const float* beta = (const float*)d_in[9];
    const float* W1   = (const float*)d_in[10];
    const float* b1   = (const float*)d_in[11];
    const float* W2   = (const float*)d_in[12];
    const float* b2   = (const float*)d_in[13];
    float* out = (float*)d_out;

    forecast_fused<<<dim3(BB), dim3(NTHREADS), 0, stream>>>(
        x, Wemb, bemb, Wd, bd, Alog, Wg, bg, gmma, beta, W1, b1, W2, b2, out);
}

// Round 7
// 216.816 us; speedup vs baseline: 8.7756x; 1.0303x over previous
//
#include <hip/hip_runtime.h>
#include <math.h>

#define BB 256
#define SS 4096
#define FF 8
#define HH 32
#define TT 128              // timesteps per LDS tile
#define NT (SS/TT)          // 32 tiles
#define NTHREADS 512
#define NG (NTHREADS/HH)    // 16 chunk groups
#define CL (TT/NG)          // 8 timesteps per chunk
#define HROW 20             // h1h row stride in dwords (16 data + 4 pad, 16B-aligned)

#define L2E  1.4426950408889634f
#define LN2f 0.6931471805599453f

typedef _Float16 half2v __attribute__((ext_vector_type(2)));
typedef __fp16   pk16   __attribute__((ext_vector_type(2)));   // cvt_pkrtz return type

__device__ __forceinline__ float fexp2(float x){
#if __has_builtin(__builtin_amdgcn_exp2f)
    return __builtin_amdgcn_exp2f(x);
#else
    return exp2f(x);
#endif
}
__device__ __forceinline__ float flog2(float x){
#if __has_builtin(__builtin_amdgcn_logf)
    return __builtin_amdgcn_logf(x);
#else
    return log2f(x);
#endif
}
__device__ __forceinline__ float frcp(float x){
#if __has_builtin(__builtin_amdgcn_rcpf)
    return __builtin_amdgcn_rcpf(x);
#else
    return 1.0f/x;
#endif
}
__device__ __forceinline__ float fdot2(half2v a, half2v b, float c){
#if __has_builtin(__builtin_amdgcn_fdot2)
    return __builtin_amdgcn_fdot2(a, b, c, false);
#else
    return c + (float)a.x*(float)b.x + (float)a.y*(float)b.y;
#endif
}

// softplus(z) = max(z,0) + ln2*log2(1 + 2^(-|z|*log2e))
__device__ __forceinline__ float softplus_n(float z){
    const float t = fexp2(-fabsf(z) * L2E);
    return fmaxf(z, 0.f) + LN2f * flog2(1.f + t);
}
// sigmoid(z) = 1/(1 + 2^(-z*log2e))
__device__ __forceinline__ float sigmoid_n(float z){
    return frcp(1.f + fexp2(-z * L2E));
}

__global__ __launch_bounds__(NTHREADS)
void forecast_fused(const float* __restrict__ x,
                    const float* __restrict__ Wemb, const float* __restrict__ bemb,
                    const float* __restrict__ Wd,   const float* __restrict__ bd,
                    const float* __restrict__ Alog,
                    const float* __restrict__ Wg,   const float* __restrict__ bg,
                    const float* __restrict__ gmma, const float* __restrict__ beta,
                    const float* __restrict__ W1,   const float* __restrict__ b1,
                    const float* __restrict__ W2,   const float* __restrict__ b2,
                    float* __restrict__ out)
{
    __shared__ __align__(16) float xs[TT * FF];            // staged x tile    4 KB
    __shared__ __align__(16) unsigned int h1h[TT][HROW];   // h1 packed f16   10 KB
    __shared__ float wdpS[FF][HH];         // Wemb@Wd1 composed
    __shared__ float wgpS[FF][HH];         // Wemb@Wg1 composed
    __shared__ float bdpS[HH], bgpS[HH];   // composed biases
    __shared__ float cfA[NG][HH];          // chunk-final prefix products
    __shared__ float cfX[NG][HH];          // chunk-final local states
    __shared__ float s1s[2][HH];           // running state, block 1 (dbuf by tile parity)
    __shared__ float hlast[HH];            // exact f32 h1 of last row (head)

    const int tid = threadIdx.x;
    const int c   = tid & (HH - 1);        // channel
    const int g   = tid >> 5;              // chunk group
    const int b   = blockIdx.x;
    const int ts0 = g * CL;

    // ---- one-time: compose block-1 weights through the embedding ----
    if (tid < FF * HH) {
        const int f = tid >> 5, cc = tid & 31;
        float accd = 0.f, accg = 0.f;
#pragma unroll
        for (int k = 0; k < HH; ++k) {
            const float w = Wemb[f * HH + k];
            accd += w * Wd[k * HH + cc];
            accg += w * Wg[k * HH + cc];
        }
        wdpS[f][cc] = accd;
        wgpS[f][cc] = accg;
    }
    if (tid < HH) {
        float ad = bd[tid], ag = bg[tid];
#pragma unroll
        for (int k = 0; k < HH; ++k) {
            ad += bemb[k] * Wd[k * HH + tid];
            ag += bemb[k] * Wg[k * HH + tid];
        }
        bdpS[tid] = ad; bgpS[tid] = ag;
        s1s[0][tid] = 0.f;
    }
    __syncthreads();

    // per-lane register weights (column c)
    float we[FF], wd1p[FF], wg1p[FF];
    half2v wh[HH/2];
#pragma unroll
    for (int f = 0; f < FF; ++f) {
        we[f]   = Wemb[f * HH + c];
        wd1p[f] = wdpS[f][c];
        wg1p[f] = wgpS[f][c];
    }
#pragma unroll
    for (int j = 0; j < HH/2; ++j) {
        half2v w2;
        w2.x = (_Float16)Wd[HH * HH + (2*j)   * HH + c];
        w2.y = (_Float16)Wd[HH * HH + (2*j+1) * HH + c];
        wh[j] = w2;
    }
    const float bec  = bemb[c];
    const float bd1p = bdpS[c], bg1p = bgpS[c], bd2 = bd[HH + c];
    const float nA1 = -expf(Alog[c]) * L2E;
    const float nA2 = -expf(Alog[HH + c]) * L2E;

    float s2v = 0.f;                       // block-2 running carry (lanes<32 of wave0)

    for (int it = 0; it < NT; ++it) {
        // ---- X: stage x tile ----
        const float2* xg2 = reinterpret_cast<const float2*>(x + ((size_t)b * SS + it * TT) * FF);
        reinterpret_cast<float2*>(xs)[tid] = xg2[tid];
        __syncthreads();

        // ---- D1: h0/zd1/zg1 straight from x (K=8); local scan in registers ----
        float prefA[CL], loc[CL], gtv[CL], h0r[CL], h1r[CL];
        {
            float sp = 1.f, sl = 0.f;
#pragma unroll
            for (int r = 0; r < CL; ++r) {
                const int ts = ts0 + r;
                const float4 xv0 = *reinterpret_cast<const float4*>(&xs[ts * FF]);
                const float4 xv1 = *reinterpret_cast<const float4*>(&xs[ts * FF + 4]);
                float h0 = bec, zd = bd1p, zg = bg1p;
                h0 += xv0.x*we[0]   + xv0.y*we[1]   + xv0.z*we[2]   + xv0.w*we[3];
                h0 += xv1.x*we[4]   + xv1.y*we[5]   + xv1.z*we[6]   + xv1.w*we[7];
                zd += xv0.x*wd1p[0] + xv0.y*wd1p[1] + xv0.z*wd1p[2] + xv0.w*wd1p[3];
                zd += xv1.x*wd1p[4] + xv1.y*wd1p[5] + xv1.z*wd1p[6] + xv1.w*wd1p[7];
                zg += xv0.x*wg1p[0] + xv0.y*wg1p[1] + xv0.z*wg1p[2] + xv0.w*wg1p[3];
                zg += xv1.x*wg1p[4] + xv1.y*wg1p[5] + xv1.z*wg1p[6] + xv1.w*wg1p[7];
                const float delta = softplus_n(zd);
                const float ab    = fexp2(delta * nA1);
                sl = ab * sl + delta * h0;
                sp *= ab;
                prefA[r] = sp;
                loc[r]   = sl;
                gtv[r]   = sigmoid_n(zg);
                h0r[r]   = h0;
            }
            cfA[g][c] = sp;
            cfX[g][c] = sl;
        }
        __syncthreads();

        // ---- COMB1: every thread computes its own carry-in (no serial wave0 phase) ----
        float ci;
        {
            float cy = s1s[it & 1][c];
#pragma unroll
            for (int ch = 0; ch < NG; ++ch) {
                const float A = cfA[ch][c];
                const float X = cfX[ch][c];
                const float t = A * cy + X;
                cy = (ch < g) ? t : cy;
            }
            ci = cy;
            if (g == NG - 1)
                s1s[(it + 1) & 1][c] = cfA[NG - 1][c] * cy + cfX[NG - 1][c];
        }

        // ---- C1: fixup + residual gate; write h1 rows as packed f16 ----
#pragma unroll
        for (int r = 0; r < CL; ++r) {
            const float st = loc[r] + prefA[r] * ci;
            const float h1 = h0r[r] + st * gtv[r];
            h1r[r] = h1;
            const float pn = __shfl_xor(h1, 1);
            if (!(c & 1)) {
                const pk16 pk = __builtin_amdgcn_cvt_pkrtz(h1, pn);
                h1h[ts0 + r][c >> 1] = __builtin_bit_cast(unsigned int, pk);
            }
        }
        if (it == NT - 1 && g == NG - 1) hlast[c] = h1r[CL - 1];
        __syncthreads();

        // ---- D2: block-2 delta path via packed-f16 dot2; local scan (scalars) ----
        {
            float sp = 1.f, sl = 0.f;
#pragma unroll
            for (int r = 0; r < CL; ++r) {
                const uint4* rp = reinterpret_cast<const uint4*>(&h1h[ts0 + r][0]);
                const uint4 q0 = rp[0], q1 = rp[1], q2 = rp[2], q3 = rp[3];
                float za = bd2, zb = 0.f;
                za = fdot2(__builtin_bit_cast(half2v, q0.x), wh[0],  za);
                zb = fdot2(__builtin_bit_cast(half2v, q0.y), wh[1],  zb);
                za = fdot2(__builtin_bit_cast(half2v, q0.z), wh[2],  za);
                zb = fdot2(__builtin_bit_cast(half2v, q0.w), wh[3],  zb);
                za = fdot2(__builtin_bit_cast(half2v, q1.x), wh[4],  za);
                zb = fdot2(__builtin_bit_cast(half2v, q1.y), wh[5],  zb);
                za = fdot2(__builtin_bit_cast(half2v, q1.z), wh[6],  za);
                zb = fdot2(__builtin_bit_cast(half2v, q1.w), wh[7],  zb);
                za = fdot2(__builtin_bit_cast(half2v, q2.x), wh[8],  za);
                zb = fdot2(__builtin_bit_cast(half2v, q2.y), wh[9],  zb);
                za = fdot2(__builtin_bit_cast(half2v, q2.z), wh[10], za);
                zb = fdot2(__builtin_bit_cast(half2v, q2.w), wh[11], zb);
                za = fdot2(__builtin_bit_cast(half2v, q3.x), wh[12], za);
                zb = fdot2(__builtin_bit_cast(half2v, q3.y), wh[13], zb);
                za = fdot2(__builtin_bit_cast(half2v, q3.z), wh[14], za);
                zb = fdot2(__builtin_bit_cast(half2v, q3.w), wh[15], zb);
                const float zd    = za + zb;
                const float delta = softplus_n(zd);
                const float ab    = fexp2(delta * nA2);
                sl = ab * sl + delta * h1r[r];
                sp *= ab;
            }
            cfA[g][c] = sp;
            cfX[g][c] = sl;
        }
        __syncthreads();

        // ---- COMB2: carry only, wave0 (others run ahead to next X; post-X barrier orders) ----
        if (tid < HH) {
            float cy = s2v;
#pragma unroll
            for (int ch = 0; ch < NG; ++ch)
                cy = cfA[ch][tid] * cy + cfX[ch][tid];
            s2v = cy;
        }
    }
    __syncthreads();

    // ---- head: gate2 on last token, residual, LN, GELU MLP -> scalar ----
    if (tid < HH) {
        float zg = bg[HH + tid];
#pragma unroll
        for (int k = 0; k < HH; ++k) zg += hlast[k] * Wg[HH * HH + k * HH + tid];
        const float gt2 = sigmoid_n(zg);
        const float h2  = hlast[tid] + s2v * gt2;

        float sum = h2;
#pragma unroll
        for (int m = 1; m < HH; m <<= 1) sum += __shfl_xor(sum, m);
        const float mu = sum * (1.0f / HH);
        const float d  = h2 - mu;
        float vs = d * d;
#pragma unroll
        for (int m = 1; m < HH; m <<= 1) vs += __shfl_xor(vs, m);
        const float rstd = rsqrtf(vs * (1.0f / HH) + 1e-5f);
        const float hn   = d * rstd * gmma[tid] + beta[tid];

        float z = b1[tid];
#pragma unroll
        for (int k = 0; k < HH; ++k) z += __shfl(hn, k) * W1[k * HH + tid];
        // gelu tanh-approx; tanh(t) = 1 - 2/(1+2^(2t*log2e))
        const float u  = 2.0f * L2E * 0.7978845608028654f * (z + 0.044715f * z * z * z);
        const float e  = fexp2(u);
        const float th = 1.f - 2.f * frcp(1.f + e);
        const float ge = 0.5f * z * (1.0f + th);
        float v = ge * W2[tid];
#pragma unroll
        for (int m = 1; m < HH; m <<= 1) v += __shfl_xor(v, m);
        if (tid == 0) out[b] = v + b2[0];
    }
}

extern "C" void kernel_launch(void* const* d_in, const int* in_sizes, int n_in,
                              void* d_out, int out_size, void* d_ws, size_t ws_size,
                              hipStream_t stream) {
    const float* x    = (const float*)d_in[0];
    const float* Wemb = (const float*)d_in[1];
    const float* bemb = (const float*)d_in[2];
    const float* Wd   = (const float*)d_in[3];
    const float* bd   = (const float*)d_in[4];
    const float* Alog = (const float*)d_in[5];
    const float* Wg   = (const float*)d_in[6];
    const float* bg   = (const float*)d_in[7];
    const float* gmma = (const float*)d_in[8];
    const float* beta = (const float*)d_in[9];
    const float* W1   = (const float*)d_in[10];
    const float* b1   = (const float*)d_in[11];
    const float* W2   = (const float*)d_in[12];
    const float* b2   = (const float*)d_in[13];
    float* out = (float*)d_out;

    forecast_fused<<<dim3(BB), dim3(NTHREADS), 0, stream>>>(
        x, Wemb, bemb, Wd, bd, Alog, Wg, bg, gmma, beta, W1, b1, W2, b2, out);
}

// Round 8
// 185.703 us; speedup vs baseline: 10.2459x; 1.1675x over previous
//
#include <hip/hip_runtime.h>
#include <math.h>

#define BB 256
#define SS 4096
#define FF 8
#define HH 32
#define TT 256              // timesteps per LDS tile
#define NT (SS/TT)          // 16 tiles
#define NTHREADS 1024
#define NG 16               // chunks per tile (one wave per chunk)
#define CL 16               // timesteps per chunk
#define SUB 8               // timesteps per thread (half chunk)

#define L2E  1.4426950408889634f
#define LN2f 0.6931471805599453f

typedef _Float16 half2v __attribute__((ext_vector_type(2)));
typedef __fp16   pk16   __attribute__((ext_vector_type(2)));   // cvt_pkrtz return type

__device__ __forceinline__ float fexp2(float x){
#if __has_builtin(__builtin_amdgcn_exp2f)
    return __builtin_amdgcn_exp2f(x);
#else
    return exp2f(x);
#endif
}
__device__ __forceinline__ float flog2(float x){
#if __has_builtin(__builtin_amdgcn_logf)
    return __builtin_amdgcn_logf(x);
#else
    return log2f(x);
#endif
}
__device__ __forceinline__ float frcp(float x){
#if __has_builtin(__builtin_amdgcn_rcpf)
    return __builtin_amdgcn_rcpf(x);
#else
    return 1.0f/x;
#endif
}
__device__ __forceinline__ float fdot2(half2v a, half2v b, float c){
#if __has_builtin(__builtin_amdgcn_fdot2)
    return __builtin_amdgcn_fdot2(a, b, c, false);
#else
    return c + (float)a.x*(float)b.x + (float)a.y*(float)b.y;
#endif
}
__device__ __forceinline__ half2v bch2(unsigned int u){
    return __builtin_bit_cast(half2v, u);
}

// softplus(z) = max(z,0) + ln2*log2(1 + 2^(-|z|*log2e))
__device__ __forceinline__ float softplus_n(float z){
    const float t = fexp2(-fabsf(z) * L2E);
    return fmaxf(z, 0.f) + LN2f * flog2(1.f + t);
}
// sigmoid(z) = 1/(1 + 2^(-z*log2e))
__device__ __forceinline__ float sigmoid_n(float z){
    return frcp(1.f + fexp2(-z * L2E));
}

__global__ __launch_bounds__(NTHREADS, 4)
void forecast_fused(const float* __restrict__ x,
                    const float* __restrict__ Wemb, const float* __restrict__ bemb,
                    const float* __restrict__ Wd,   const float* __restrict__ bd,
                    const float* __restrict__ Alog,
                    const float* __restrict__ Wg,   const float* __restrict__ bg,
                    const float* __restrict__ gmma, const float* __restrict__ beta,
                    const float* __restrict__ W1,   const float* __restrict__ b1,
                    const float* __restrict__ W2,   const float* __restrict__ b2,
                    float* __restrict__ out)
{
    __shared__ __align__(16) unsigned int xs16[TT][4];   // x tile packed f16   4 KB
    __shared__ __align__(16) unsigned int h1h[TT][16];   // h1 packed f16      16 KB
    __shared__ float wdpS[FF][HH];         // Wemb@Wd1 composed
    __shared__ float wgpS[FF][HH];         // Wemb@Wg1 composed
    __shared__ float bdpS[HH], bgpS[HH];   // composed biases
    __shared__ float2 cfS[NG][HH];         // chunk totals (A, X)               4 KB
    __shared__ float s1s[2][HH];           // block-1 running state (parity dbuf)
    __shared__ float hlast[HH];            // exact f32 h1 of last row (head)

    const int tid = threadIdx.x;
    const int c   = tid & (HH - 1);        // channel
    const int s   = (tid >> 5) & 1;        // half-chunk (0: first 8 ts, 1: last 8)
    const int g   = tid >> 6;              // chunk index == wave index
    const int b   = blockIdx.x;
    const int tsb = g * CL + s * SUB;

    // ---- one-time: compose block-1 weights through the embedding ----
    // zd1 = h0@Wd1+bd1 = x@(We@Wd1) + (be@Wd1+bd1); same for zg1.
    if (tid < FF * HH) {
        const int f = tid >> 5, cc = tid & 31;
        float accd = 0.f, accg = 0.f;
#pragma unroll
        for (int k = 0; k < HH; ++k) {
            const float w = Wemb[f * HH + k];
            accd += w * Wd[k * HH + cc];
            accg += w * Wg[k * HH + cc];
        }
        wdpS[f][cc] = accd;
        wgpS[f][cc] = accg;
    }
    if (tid < HH) {
        float ad = bd[tid], ag = bg[tid];
#pragma unroll
        for (int k = 0; k < HH; ++k) {
            ad += bemb[k] * Wd[k * HH + tid];
            ag += bemb[k] * Wg[k * HH + tid];
        }
        bdpS[tid] = ad; bgpS[tid] = ag;
        s1s[0][tid] = 0.f;
    }
    __syncthreads();

    // ---- per-lane register weights (column c), f16-packed over the K dim ----
    half2v weh[FF/2], wdh[FF/2], wgh[FF/2], wh[HH/2];
#pragma unroll
    for (int j = 0; j < FF/2; ++j) {
        half2v a;
        a.x = (_Float16)Wemb[(2*j) * HH + c];   a.y = (_Float16)Wemb[(2*j+1) * HH + c];
        weh[j] = a;
        a.x = (_Float16)wdpS[2*j][c];           a.y = (_Float16)wdpS[2*j+1][c];
        wdh[j] = a;
        a.x = (_Float16)wgpS[2*j][c];           a.y = (_Float16)wgpS[2*j+1][c];
        wgh[j] = a;
    }
#pragma unroll
    for (int j = 0; j < HH/2; ++j) {
        half2v a;
        a.x = (_Float16)Wd[HH * HH + (2*j)   * HH + c];
        a.y = (_Float16)Wd[HH * HH + (2*j+1) * HH + c];
        wh[j] = a;
    }
    const float bec  = bemb[c];
    const float bd1p = bdpS[c], bg1p = bgpS[c], bd2 = bd[HH + c];
    const float nA1 = -expf(Alog[c]) * L2E;
    const float nA2 = -expf(Alog[HH + c]) * L2E;

    float s2v = 0.f;                       // block-2 running carry (wave0 lanes<32)

    for (int it = 0; it < NT; ++it) {
        // ---- X: stage x tile as packed f16 (coalesced float2 loads) ----
        {
            const int row = tid >> 2, dc = tid & 3;
            const float2 xv = *reinterpret_cast<const float2*>(
                x + ((size_t)b * SS + it * TT + row) * FF + dc * 2);
            const pk16 pk = __builtin_amdgcn_cvt_pkrtz(xv.x, xv.y);
            xs16[row][dc] = __builtin_bit_cast(unsigned int, pk);
        }
        __syncthreads();

        // ---- D1: h0/zd1/zg1 via f16 dot2 (K=8); half-chunk local scan in regs ----
        float prefA[SUB], loc[SUB], gtv[SUB], h0r[SUB], h1r[SUB];
        float sp = 1.f, sl = 0.f;
#pragma unroll
        for (int r = 0; r < SUB; ++r) {
            const int ts = tsb + r;
            const uint4 xq = *reinterpret_cast<const uint4*>(&xs16[ts][0]);
            float h0 = bec, zd = bd1p, zg = bg1p;
            h0 = fdot2(bch2(xq.x), weh[0], h0);
            h0 = fdot2(bch2(xq.y), weh[1], h0);
            h0 = fdot2(bch2(xq.z), weh[2], h0);
            h0 = fdot2(bch2(xq.w), weh[3], h0);
            zd = fdot2(bch2(xq.x), wdh[0], zd);
            zd = fdot2(bch2(xq.y), wdh[1], zd);
            zd = fdot2(bch2(xq.z), wdh[2], zd);
            zd = fdot2(bch2(xq.w), wdh[3], zd);
            zg = fdot2(bch2(xq.x), wgh[0], zg);
            zg = fdot2(bch2(xq.y), wgh[1], zg);
            zg = fdot2(bch2(xq.z), wgh[2], zg);
            zg = fdot2(bch2(xq.w), wgh[3], zg);
            const float delta = softplus_n(zd);
            const float ab    = fexp2(delta * nA1);
            sl = ab * sl + delta * h0;
            sp *= ab;
            prefA[r] = sp;
            loc[r]   = sl;
            gtv[r]   = sigmoid_n(zg);
            h0r[r]   = h0;
        }
        // half-chunk exchange (partner = same c, other s; same wave)
        const float spO = __shfl_xor(sp, 32);
        const float slO = __shfl_xor(sl, 32);
        if (s) cfS[g][c] = make_float2(spO * sp, sp * slO + sl);   // chunk totals
        __syncthreads();

        // ---- COMB1: wave-uniform chain over preceding chunks ----
        float cy = s1s[it & 1][c];
        for (int ch = 0; ch < g; ++ch) {          // trip count uniform per wave
            const float2 ax = cfS[ch][c];
            cy = ax.x * cy + ax.y;
        }
        const float ci = s ? (slO + spO * cy) : cy;   // carry into this half
        if (g == NG - 1 && s) s1s[(it + 1) & 1][c] = sl + sp * ci;

        // ---- C1: fixup + residual gate; h1 rows as packed f16 ----
#pragma unroll
        for (int r = 0; r < SUB; ++r) {
            const float st = loc[r] + prefA[r] * ci;
            const float h1 = h0r[r] + st * gtv[r];
            h1r[r] = h1;
            const float pn = __shfl_xor(h1, 1);
            if (!(c & 1)) {
                const pk16 pk = __builtin_amdgcn_cvt_pkrtz(h1, pn);
                h1h[tsb + r][c >> 1] = __builtin_bit_cast(unsigned int, pk);
            }
        }
        if (it == NT - 1 && g == NG - 1 && s) hlast[c] = h1r[SUB - 1];
        __syncthreads();

        // ---- D2: block-2 delta via packed-f16 dot2; half-chunk local scan ----
        float sp2 = 1.f, sl2 = 0.f;
#pragma unroll
        for (int r = 0; r < SUB; ++r) {
            const uint4* rp = reinterpret_cast<const uint4*>(&h1h[tsb + r][0]);
            const uint4 q0 = rp[0], q1 = rp[1], q2 = rp[2], q3 = rp[3];
            float za = bd2, zb = 0.f;
            za = fdot2(bch2(q0.x), wh[0],  za);
            zb = fdot2(bch2(q0.y), wh[1],  zb);
            za = fdot2(bch2(q0.z), wh[2],  za);
            zb = fdot2(bch2(q0.w), wh[3],  zb);
            za = fdot2(bch2(q1.x), wh[4],  za);
            zb = fdot2(bch2(q1.y), wh[5],  zb);
            za = fdot2(bch2(q1.z), wh[6],  za);
            zb = fdot2(bch2(q1.w), wh[7],  zb);
            za = fdot2(bch2(q2.x), wh[8],  za);
            zb = fdot2(bch2(q2.y), wh[9],  zb);
            za = fdot2(bch2(q2.z), wh[10], za);
            zb = fdot2(bch2(q2.w), wh[11], zb);
            za = fdot2(bch2(q3.x), wh[12], za);
            zb = fdot2(bch2(q3.y), wh[13], zb);
            za = fdot2(bch2(q3.z), wh[14], za);
            zb = fdot2(bch2(q3.w), wh[15], zb);
            const float zd    = za + zb;
            const float delta = softplus_n(zd);
            const float ab    = fexp2(delta * nA2);
            sl2 = ab * sl2 + delta * h1r[r];
            sp2 *= ab;
        }
        const float spO2 = __shfl_xor(sp2, 32);
        const float slO2 = __shfl_xor(sl2, 32);
        if (s) cfS[g][c] = make_float2(spO2 * sp2, sp2 * slO2 + sl2);
        __syncthreads();

        // ---- COMB2: carry only (wave0 lanes<32; others run ahead to next X) ----
        if (tid < HH) {
            float cy2 = s2v;
#pragma unroll
            for (int ch = 0; ch < NG; ++ch) {
                const float2 ax = cfS[ch][tid];
                cy2 = ax.x * cy2 + ax.y;
            }
            s2v = cy2;
        }
        // safe: next cfS write is at end of next D1, behind the post-X barrier,
        // which wave0 only reaches after COMB2 completes.
    }
    __syncthreads();

    // ---- head: gate2 on last token, residual, LN, GELU MLP -> scalar ----
    if (tid < HH) {
        float zg = bg[HH + tid];
#pragma unroll
        for (int k = 0; k < HH; ++k) zg += hlast[k] * Wg[HH * HH + k * HH + tid];
        const float gt2 = sigmoid_n(zg);
        const float h2  = hlast[tid] + s2v * gt2;

        float sum = h2;
#pragma unroll
        for (int m = 1; m < HH; m <<= 1) sum += __shfl_xor(sum, m);
        const float mu = sum * (1.0f / HH);
        const float d  = h2 - mu;
        float vs = d * d;
#pragma unroll
        for (int m = 1; m < HH; m <<= 1) vs += __shfl_xor(vs, m);
        const float rstd = rsqrtf(vs * (1.0f / HH) + 1e-5f);
        const float hn   = d * rstd * gmma[tid] + beta[tid];

        float z = b1[tid];
#pragma unroll
        for (int k = 0; k < HH; ++k) z += __shfl(hn, k) * W1[k * HH + tid];
        // gelu tanh-approx; tanh(t) = 1 - 2/(1+2^(2t*log2e))
        const float u  = 2.0f * L2E * 0.7978845608028654f * (z + 0.044715f * z * z * z);
        const float e  = fexp2(u);
        const float th = 1.f - 2.f * frcp(1.f + e);
        const float ge = 0.5f * z * (1.0f + th);
        float v = ge * W2[tid];
#pragma unroll
        for (int m = 1; m < HH; m <<= 1) v += __shfl_xor(v, m);
        if (tid == 0) out[b] = v + b2[0];
    }
}

extern "C" void kernel_launch(void* const* d_in, const int* in_sizes, int n_in,
                              void* d_out, int out_size, void* d_ws, size_t ws_size,
                              hipStream_t stream) {
    const float* x    = (const float*)d_in[0];
    const float* Wemb = (const float*)d_in[1];
    const float* bemb = (const float*)d_in[2];
    const float* Wd   = (const float*)d_in[3];
    const float* bd   = (const float*)d_in[4];
    const float* Alog = (const float*)d_in[5];
    const float* Wg   = (const float*)d_in[6];
    const float* bg   = (const float*)d_in[7];
    const float* gmma = (const float*)d_in[8];
    const float* beta = (const float*)d_in[9];
    const float* W1   = (const float*)d_in[10];
    const float* b1   = (const float*)d_in[11];
    const float* W2   = (const float*)d_in[12];
    const float* b2   = (const float*)d_in[13];
    float* out = (float*)d_out;

    forecast_fused<<<dim3(BB), dim3(NTHREADS), 0, stream>>>(
        x, Wemb, bemb, Wd, bd, Alog, Wg, bg, gmma, beta, W1, b1, W2, b2, out);
}

// Round 9
// 181.766 us; speedup vs baseline: 10.4678x; 1.0217x over previous
//
#include <hip/hip_runtime.h>
#include <math.h>

#define BB 256
#define SS 4096
#define FF 8
#define HH 32
#define TT 256              // timesteps per LDS tile
#define NT (SS/TT)          // 16 tiles
#define NTHREADS 1024
#define NG 16               // chunks per tile (one wave per chunk)
#define CL 16               // timesteps per chunk
#define SUB 8               // timesteps per thread (half chunk)

#define L2E  1.4426950408889634f
#define LN2f 0.6931471805599453f

typedef _Float16 half2v __attribute__((ext_vector_type(2)));
typedef __fp16   pk16   __attribute__((ext_vector_type(2)));   // cvt_pkrtz return type

__device__ __forceinline__ float fexp2(float x){
#if __has_builtin(__builtin_amdgcn_exp2f)
    return __builtin_amdgcn_exp2f(x);
#else
    return exp2f(x);
#endif
}
__device__ __forceinline__ float flog2(float x){
#if __has_builtin(__builtin_amdgcn_logf)
    return __builtin_amdgcn_logf(x);
#else
    return log2f(x);
#endif
}
__device__ __forceinline__ float frcp(float x){
#if __has_builtin(__builtin_amdgcn_rcpf)
    return __builtin_amdgcn_rcpf(x);
#else
    return 1.0f/x;
#endif
}
__device__ __forceinline__ float fdot2(half2v a, half2v b, float c){
#if __has_builtin(__builtin_amdgcn_fdot2)
    return __builtin_amdgcn_fdot2(a, b, c, false);
#else
    return c + (float)a.x*(float)b.x + (float)a.y*(float)b.y;
#endif
}
__device__ __forceinline__ half2v bch2(unsigned int u){
    return __builtin_bit_cast(half2v, u);
}

// softplus(z) = max(z,0) + ln2*log2(1 + 2^(-|z|*log2e))
__device__ __forceinline__ float softplus_n(float z){
    const float t = fexp2(-fabsf(z) * L2E);
    return fmaxf(z, 0.f) + LN2f * flog2(1.f + t);
}
// sigmoid(z) = 1/(1 + 2^(-z*log2e))
__device__ __forceinline__ float sigmoid_n(float z){
    return frcp(1.f + fexp2(-z * L2E));
}

__global__ __launch_bounds__(NTHREADS, 4)
void forecast_fused(const float* __restrict__ x,
                    const float* __restrict__ Wemb, const float* __restrict__ bemb,
                    const float* __restrict__ Wd,   const float* __restrict__ bd,
                    const float* __restrict__ Alog,
                    const float* __restrict__ Wg,   const float* __restrict__ bg,
                    const float* __restrict__ gmma, const float* __restrict__ beta,
                    const float* __restrict__ W1,   const float* __restrict__ b1,
                    const float* __restrict__ W2,   const float* __restrict__ b2,
                    float* __restrict__ out)
{
    __shared__ __align__(16) unsigned int xs16[2][TT][4]; // x tile f16, parity dbuf  8 KB
    __shared__ __align__(16) unsigned int h1h[TT][16];    // h1 packed f16           16 KB
    __shared__ float wdpS[FF][HH];         // Wemb@Wd1 composed
    __shared__ float wgpS[FF][HH];         // Wemb@Wg1 composed
    __shared__ float bdpS[HH], bgpS[HH];   // composed biases
    __shared__ float2 cfS[2][NG][HH];      // chunk totals (A,X), parity dbuf   8 KB
    __shared__ float s1s[2][HH];           // block-1 running state (parity dbuf)
    __shared__ float hlast[HH];            // exact f32 h1 of last row (head)

    const int tid = threadIdx.x;
    const int c   = tid & (HH - 1);        // channel
    const int s   = (tid >> 5) & 1;        // half-chunk (0: first 8 ts, 1: last 8)
    const int g   = tid >> 6;              // chunk index == wave index
    const int b   = blockIdx.x;
    const int tsb = g * CL + s * SUB;
    const int xrow = tid >> 2, xdc = tid & 3;   // X-staging assignment

    // ---- one-time: compose block-1 weights through the embedding ----
    // zd1 = h0@Wd1+bd1 = x@(We@Wd1) + (be@Wd1+bd1); same for zg1.
    if (tid < FF * HH) {
        const int f = tid >> 5, cc = tid & 31;
        float accd = 0.f, accg = 0.f;
#pragma unroll
        for (int k = 0; k < HH; ++k) {
            const float w = Wemb[f * HH + k];
            accd += w * Wd[k * HH + cc];
            accg += w * Wg[k * HH + cc];
        }
        wdpS[f][cc] = accd;
        wgpS[f][cc] = accg;
    }
    if (tid < HH) {
        float ad = bd[tid], ag = bg[tid];
#pragma unroll
        for (int k = 0; k < HH; ++k) {
            ad += bemb[k] * Wd[k * HH + tid];
            ag += bemb[k] * Wg[k * HH + tid];
        }
        bdpS[tid] = ad; bgpS[tid] = ag;
        s1s[0][tid] = 0.f;
    }
    __syncthreads();

    // ---- per-lane register weights (column c), f16-packed over the K dim ----
    half2v weh[FF/2], wdh[FF/2], wgh[FF/2], wh[HH/2];
#pragma unroll
    for (int j = 0; j < FF/2; ++j) {
        half2v a;
        a.x = (_Float16)Wemb[(2*j) * HH + c];   a.y = (_Float16)Wemb[(2*j+1) * HH + c];
        weh[j] = a;
        a.x = (_Float16)wdpS[2*j][c];           a.y = (_Float16)wdpS[2*j+1][c];
        wdh[j] = a;
        a.x = (_Float16)wgpS[2*j][c];           a.y = (_Float16)wgpS[2*j+1][c];
        wgh[j] = a;
    }
#pragma unroll
    for (int j = 0; j < HH/2; ++j) {
        half2v a;
        a.x = (_Float16)Wd[HH * HH + (2*j)   * HH + c];
        a.y = (_Float16)Wd[HH * HH + (2*j+1) * HH + c];
        wh[j] = a;
    }
    const float bec  = bemb[c];
    const float bd1p = bdpS[c], bg1p = bgpS[c], bd2 = bd[HH + c];
    const float nA1 = -expf(Alog[c]) * L2E;
    const float nA2 = -expf(Alog[HH + c]) * L2E;

    float s2v = 0.f;                       // block-2 running carry (wave0 lanes<32)

    // ---- prologue: stage tile 0 ----
    {
        const float2 xv = *reinterpret_cast<const float2*>(
            x + ((size_t)b * SS + xrow) * FF + xdc * 2);
        const pk16 pk = __builtin_amdgcn_cvt_pkrtz(xv.x, xv.y);
        xs16[0][xrow][xdc] = __builtin_bit_cast(unsigned int, pk);
    }
    __syncthreads();

    for (int it = 0; it < NT; ++it) {
        const int p = it & 1;

        // ---- prefetch next x tile into registers (latency hides under D1..D2) ----
        float2 xnext;
        if (it + 1 < NT)
            xnext = *reinterpret_cast<const float2*>(
                x + ((size_t)b * SS + (it + 1) * TT + xrow) * FF + xdc * 2);

        // ---- D1: h0/zd1/zg1 via f16 dot2 (K=8); half-chunk local scan in regs ----
        float prefA[SUB], loc[SUB], gtv[SUB], h0r[SUB], h1r[SUB];
        float sp = 1.f, sl = 0.f;
#pragma unroll
        for (int r = 0; r < SUB; ++r) {
            const int ts = tsb + r;
            const uint4 xq = *reinterpret_cast<const uint4*>(&xs16[p][ts][0]);
            float h0 = bec, zd = bd1p, zg = bg1p;
            h0 = fdot2(bch2(xq.x), weh[0], h0);
            h0 = fdot2(bch2(xq.y), weh[1], h0);
            h0 = fdot2(bch2(xq.z), weh[2], h0);
            h0 = fdot2(bch2(xq.w), weh[3], h0);
            zd = fdot2(bch2(xq.x), wdh[0], zd);
            zd = fdot2(bch2(xq.y), wdh[1], zd);
            zd = fdot2(bch2(xq.z), wdh[2], zd);
            zd = fdot2(bch2(xq.w), wdh[3], zd);
            zg = fdot2(bch2(xq.x), wgh[0], zg);
            zg = fdot2(bch2(xq.y), wgh[1], zg);
            zg = fdot2(bch2(xq.z), wgh[2], zg);
            zg = fdot2(bch2(xq.w), wgh[3], zg);
            const float delta = softplus_n(zd);
            const float ab    = fexp2(delta * nA1);
            sl = ab * sl + delta * h0;
            sp *= ab;
            prefA[r] = sp;
            loc[r]   = sl;
            gtv[r]   = sigmoid_n(zg);
            h0r[r]   = h0;
        }
        // half-chunk exchange (partner = same c, other s; same wave)
        const float spO = __shfl_xor(sp, 32);
        const float slO = __shfl_xor(sl, 32);
        if (s) cfS[p][g][c] = make_float2(spO * sp, sp * slO + sl);   // chunk totals
        __syncthreads();                                              // B2

        // ---- COMB1: fully-unrolled predicated chain (batched LDS reads) ----
        float cy = s1s[p][c];
#pragma unroll
        for (int ch = 0; ch < NG; ++ch) {
            const float2 ax = cfS[p][ch][c];
            const float t = ax.x * cy + ax.y;
            cy = (ch < g) ? t : cy;
        }
        const float ci = s ? (slO + spO * cy) : cy;   // carry into this half
        if (g == NG - 1 && s) s1s[p ^ 1][c] = sl + sp * ci;

        // ---- C1: fixup + residual gate; h1 rows as packed f16 ----
#pragma unroll
        for (int r = 0; r < SUB; ++r) {
            const float st = loc[r] + prefA[r] * ci;
            const float h1 = h0r[r] + st * gtv[r];
            h1r[r] = h1;
            const float pn = __shfl_xor(h1, 1);
            if (!(c & 1)) {
                const pk16 pk = __builtin_amdgcn_cvt_pkrtz(h1, pn);
                h1h[tsb + r][c >> 1] = __builtin_bit_cast(unsigned int, pk);
            }
        }
        if (it == NT - 1 && g == NG - 1 && s) hlast[c] = h1r[SUB - 1];
        __syncthreads();                                              // B3

        // ---- D2: block-2 delta via packed-f16 dot2; commit prefetched x tile ----
        float sp2 = 1.f, sl2 = 0.f;
#pragma unroll
        for (int r = 0; r < SUB; ++r) {
            const uint4* rp = reinterpret_cast<const uint4*>(&h1h[tsb + r][0]);
            const uint4 q0 = rp[0], q1 = rp[1], q2 = rp[2], q3 = rp[3];
            float za = bd2, zb = 0.f;
            za = fdot2(bch2(q0.x), wh[0],  za);
            zb = fdot2(bch2(q0.y), wh[1],  zb);
            za = fdot2(bch2(q0.z), wh[2],  za);
            zb = fdot2(bch2(q0.w), wh[3],  zb);
            za = fdot2(bch2(q1.x), wh[4],  za);
            zb = fdot2(bch2(q1.y), wh[5],  zb);
            za = fdot2(bch2(q1.z), wh[6],  za);
            zb = fdot2(bch2(q1.w), wh[7],  zb);
            za = fdot2(bch2(q2.x), wh[8],  za);
            zb = fdot2(bch2(q2.y), wh[9],  zb);
            za = fdot2(bch2(q2.z), wh[10], za);
            zb = fdot2(bch2(q2.w), wh[11], zb);
            za = fdot2(bch2(q3.x), wh[12], za);
            zb = fdot2(bch2(q3.y), wh[13], zb);
            za = fdot2(bch2(q3.z), wh[14], za);
            zb = fdot2(bch2(q3.w), wh[15], zb);
            const float zd    = za + zb;
            const float delta = softplus_n(zd);
            const float ab    = fexp2(delta * nA2);
            sl2 = ab * sl2 + delta * h1r[r];
            sp2 *= ab;
        }
        const float spO2 = __shfl_xor(sp2, 32);
        const float slO2 = __shfl_xor(sl2, 32);
        if (s) cfS[p][g][c] = make_float2(spO2 * sp2, sp2 * slO2 + sl2);
        if (it + 1 < NT) {      // commit prefetched x tile to the other parity
            const pk16 pk = __builtin_amdgcn_cvt_pkrtz(xnext.x, xnext.y);
            xs16[p ^ 1][xrow][xdc] = __builtin_bit_cast(unsigned int, pk);
        }
        __syncthreads();                                              // B4

        // ---- COMB2: carry only (wave0 lanes<32; others run ahead into D1(it+1),
        //      which writes cfS[p^1] — parity dbuf makes this race-free; B2(it+1)
        //      can't be passed until wave0 finishes here) ----
        if (tid < HH) {
            float cy2 = s2v;
#pragma unroll
            for (int ch = 0; ch < NG; ++ch) {
                const float2 ax = cfS[p][ch][tid];
                cy2 = ax.x * cy2 + ax.y;
            }
            s2v = cy2;
        }
    }
    __syncthreads();

    // ---- head: gate2 on last token, residual, LN, GELU MLP -> scalar ----
    if (tid < HH) {
        float zg = bg[HH + tid];
#pragma unroll
        for (int k = 0; k < HH; ++k) zg += hlast[k] * Wg[HH * HH + k * HH + tid];
        const float gt2 = sigmoid_n(zg);
        const float h2  = hlast[tid] + s2v * gt2;

        float sum = h2;
#pragma unroll
        for (int m = 1; m < HH; m <<= 1) sum += __shfl_xor(sum, m);
        const float mu = sum * (1.0f / HH);
        const float d  = h2 - mu;
        float vs = d * d;
#pragma unroll
        for (int m = 1; m < HH; m <<= 1) vs += __shfl_xor(vs, m);
        const float rstd = rsqrtf(vs * (1.0f / HH) + 1e-5f);
        const float hn   = d * rstd * gmma[tid] + beta[tid];

        float z = b1[tid];
#pragma unroll
        for (int k = 0; k < HH; ++k) z += __shfl(hn, k) * W1[k * HH + tid];
        // gelu tanh-approx; tanh(t) = 1 - 2/(1+2^(2t*log2e))
        const float u  = 2.0f * L2E * 0.7978845608028654f * (z + 0.044715f * z * z * z);
        const float e  = fexp2(u);
        const float th = 1.f - 2.f * frcp(1.f + e);
        const float ge = 0.5f * z * (1.0f + th);
        float v = ge * W2[tid];
#pragma unroll
        for (int m = 1; m < HH; m <<= 1) v += __shfl_xor(v, m);
        if (tid == 0) out[b] = v + b2[0];
    }
}

extern "C" void kernel_launch(void* const* d_in, const int* in_sizes, int n_in,
                              void* d_out, int out_size, void* d_ws, size_t ws_size,
                              hipStream_t stream) {
    const float* x    = (const float*)d_in[0];
    const float* Wemb = (const float*)d_in[1];
    const float* bemb = (const float*)d_in[2];
    const float* Wd   = (const float*)d_in[3];
    const float* bd   = (const float*)d_in[4];
    const float* Alog = (const float*)d_in[5];
    const float* Wg   = (const float*)d_in[6];
    const float* bg   = (const float*)d_in[7];
    const float* gmma = (const float*)d_in[8];
    const float* beta = (const float*)d_in[9];
    const float* W1   = (const float*)d_in[10];
    const float* b1   = (const float*)d_in[11];
    const float* W2   = (const float*)d_in[12];
    const float* b2   = (const float*)d_in[13];
    float* out = (float*)d_out;

    forecast_fused<<<dim3(BB), dim3(NTHREADS), 0, stream>>>(
        x, Wemb, bemb, Wd, bd, Alog, Wg, bg, gmma, beta, W1, b1, W2, b2, out);
}

// Round 10
// 167.021 us; speedup vs baseline: 11.3919x; 1.0883x over previous
//
#include <hip/hip_runtime.h>
#include <math.h>

#define BB 256
#define SS 4096
#define FF 8
#define HH 32
#define TT 256              // timesteps per LDS tile
#define NT (SS/TT)          // 16 tiles
#define NTHREADS 1024
#define NG 16               // chunks per tile (one wave per chunk)
#define CLR 16              // rows per chunk

#define L2E  1.4426950408889634f
#define LN2f 0.6931471805599453f

typedef _Float16 f16x8 __attribute__((ext_vector_type(8)));
typedef float    f32x4 __attribute__((ext_vector_type(4)));
typedef __fp16   pk16  __attribute__((ext_vector_type(2)));   // cvt_pkrtz return type

__device__ __forceinline__ float fexp2(float x){
#if __has_builtin(__builtin_amdgcn_exp2f)
    return __builtin_amdgcn_exp2f(x);
#else
    return exp2f(x);
#endif
}
__device__ __forceinline__ float flog2(float x){
#if __has_builtin(__builtin_amdgcn_logf)
    return __builtin_amdgcn_logf(x);
#else
    return log2f(x);
#endif
}
__device__ __forceinline__ float frcp(float x){
#if __has_builtin(__builtin_amdgcn_rcpf)
    return __builtin_amdgcn_rcpf(x);
#else
    return 1.0f/x;
#endif
}

// softplus(z) = max(z,0) + ln2*log2(1 + 2^(-|z|*log2e))
__device__ __forceinline__ float softplus_n(float z){
    const float t = fexp2(-fabsf(z) * L2E);
    return fmaxf(z, 0.f) + LN2f * flog2(1.f + t);
}
// sigmoid(z) = 1/(1 + 2^(-z*log2e))
__device__ __forceinline__ float sigmoid_n(float z){
    return frcp(1.f + fexp2(-z * L2E));
}

__global__ __launch_bounds__(NTHREADS, 4)
void forecast_fused(const float* __restrict__ x,
                    const float* __restrict__ Wemb, const float* __restrict__ bemb,
                    const float* __restrict__ Wd,   const float* __restrict__ bd,
                    const float* __restrict__ Alog,
                    const float* __restrict__ Wg,   const float* __restrict__ bg,
                    const float* __restrict__ gmma, const float* __restrict__ beta,
                    const float* __restrict__ W1,   const float* __restrict__ b1,
                    const float* __restrict__ W2,   const float* __restrict__ b2,
                    float* __restrict__ out)
{
    __shared__ __align__(16) unsigned int xs16[2][TT][4]; // x tile f16, parity dbuf  8 KB
    __shared__ __align__(16) unsigned int h1h[TT][16];    // h1 packed f16           16 KB
    __shared__ float wdpS[FF][HH];         // Wemb@Wd1 composed
    __shared__ float wgpS[FF][HH];         // Wemb@Wg1 composed
    __shared__ float bdpS[HH], bgpS[HH];   // composed biases
    __shared__ float2 cfS[2][NG][HH];      // block-1 chunk totals (A,X), parity dbuf
    __shared__ float2 cf2S[2][NG][HH];     // block-2 chunk totals (A,X), parity dbuf
    __shared__ float s1s[2][HH];           // block-1 running state (parity dbuf)
    __shared__ float hlast[HH];            // exact f32 h1 of last row (head)

    const int tid  = threadIdx.x;
    const int lane = tid & 63;
    const int g    = tid >> 6;             // chunk index == wave index
    const int c0   = lane & 15;            // MFMA D col (channel, low half)
    const int grp  = lane >> 4;            // lane group 0..3 -> rows grp*4..+3
    const int r0   = grp * 4;
    const int cb   = g * CLR;              // chunk row base
    const int b    = blockIdx.x;
    const int xrow = tid >> 2, xdc = tid & 3;   // X-staging assignment
    const int lm16 = (lane - 16) & 63, lm32 = (lane - 32) & 63;

    // ---- one-time: compose block-1 weights through the embedding ----
    if (tid < FF * HH) {
        const int f = tid >> 5, cc = tid & 31;
        float accd = 0.f, accg = 0.f;
#pragma unroll
        for (int k = 0; k < HH; ++k) {
            const float w = Wemb[f * HH + k];
            accd += w * Wd[k * HH + cc];
            accg += w * Wg[k * HH + cc];
        }
        wdpS[f][cc] = accd;
        wgpS[f][cc] = accg;
    }
    if (tid < HH) {
        float ad = bd[tid], ag = bg[tid];
#pragma unroll
        for (int k = 0; k < HH; ++k) {
            ad += bemb[k] * Wd[k * HH + tid];
            ag += bemb[k] * Wg[k * HH + tid];
        }
        bdpS[tid] = ad; bgpS[tid] = ag;
        s1s[0][tid] = 0.f;
    }
    __syncthreads();

    // ---- B-fragments (k = (lane>>4)*8 + j; same chosen k-order for A and B)
    //      and per-channel constants for this lane's two columns ----
    f16x8 bh0[2], bzd[2], bzg[2], bwd2[2];
    float bec[2], bd1p[2], bg1p[2], bd2c[2], nA1[2], nA2[2];
#pragma unroll
    for (int q = 0; q < 2; ++q) {
        const int cq = c0 + 16 * q;
#pragma unroll
        for (int j = 0; j < 8; ++j) {
            // D1 operands: K=8 padded to 32 -> only k-block 0 (lanes<16) is real
            bh0[q][j] = (lane < 16) ? (_Float16)Wemb[j * HH + cq] : (_Float16)0.f;
            bzd[q][j] = (lane < 16) ? (_Float16)wdpS[j][cq]       : (_Float16)0.f;
            bzg[q][j] = (lane < 16) ? (_Float16)wgpS[j][cq]       : (_Float16)0.f;
            // D2 operand: full K=32
            bwd2[q][j] = (_Float16)Wd[HH * HH + (grp * 8 + j) * HH + cq];
        }
        bec[q]  = bemb[cq];
        bd1p[q] = bdpS[cq]; bg1p[q] = bgpS[cq];
        bd2c[q] = bd[HH + cq];
        nA1[q] = -expf(Alog[cq]) * L2E;
        nA2[q] = -expf(Alog[HH + cq]) * L2E;
    }

    float s2v = 0.f;                       // block-2 running carry (wave0 lanes<32)

    // ---- prologue: stage tile 0 ----
    {
        const float2 xv = *reinterpret_cast<const float2*>(
            x + ((size_t)b * SS + xrow) * FF + xdc * 2);
        const pk16 pk = __builtin_amdgcn_cvt_pkrtz(xv.x, xv.y);
        xs16[0][xrow][xdc] = __builtin_bit_cast(unsigned int, pk);
    }
    __syncthreads();

    for (int it = 0; it < NT; ++it) {
        const int p = it & 1;

        // ---- prefetch next x tile into registers ----
        float2 xnext = make_float2(0.f, 0.f);
        if (it + 1 < NT)
            xnext = *reinterpret_cast<const float2*>(
                x + ((size_t)b * SS + (it + 1) * TT + xrow) * FF + xdc * 2);

        // ---- D1: h0/zd1/zg1 via MFMA (A = x rows, K=8 padded) ----
        uint4 aw = make_uint4(0u, 0u, 0u, 0u);
        if (lane < 16) aw = *reinterpret_cast<const uint4*>(&xs16[p][cb + c0][0]);
        const f16x8 a1 = __builtin_bit_cast(f16x8, aw);
        f32x4 vh0[2], vzd[2], vzg[2];
#pragma unroll
        for (int q = 0; q < 2; ++q) {
            f32x4 cin;
            cin[0] = cin[1] = cin[2] = cin[3] = bec[q];
            vh0[q] = __builtin_amdgcn_mfma_f32_16x16x32_f16(a1, bh0[q], cin, 0, 0, 0);
            cin[0] = cin[1] = cin[2] = cin[3] = bd1p[q];
            vzd[q] = __builtin_amdgcn_mfma_f32_16x16x32_f16(a1, bzd[q], cin, 0, 0, 0);
            cin[0] = cin[1] = cin[2] = cin[3] = bg1p[q];
            vzg[q] = __builtin_amdgcn_mfma_f32_16x16x32_f16(a1, bzg[q], cin, 0, 0, 0);
        }

        // ---- pointwise + group-local (4-row) scan, all in registers ----
        float pA[2][4], pl[2][4], gt[2][4], h1v[2][4];
#pragma unroll
        for (int q = 0; q < 2; ++q) {
            float sp = 1.f, sl = 0.f;
#pragma unroll
            for (int j = 0; j < 4; ++j) {
                const float delta = softplus_n(vzd[q][j]);
                const float ab    = fexp2(delta * nA1[q]);
                sl = ab * sl + delta * vh0[q][j];
                sp *= ab;
                pA[q][j] = sp; pl[q][j] = sl;
                gt[q][j] = sigmoid_n(vzg[q][j]);
            }
        }
        // Kogge-Stone inclusive scan of (A,X) over the 4 lane-groups
        float P[2], S[2];
        P[0] = pA[0][3]; S[0] = pl[0][3];
        P[1] = pA[1][3]; S[1] = pl[1][3];
#pragma unroll
        for (int q = 0; q < 2; ++q) {
            float Pm = __shfl(P[q], lm16), Sm = __shfl(S[q], lm16);
            if (grp >= 1) { S[q] = P[q] * Sm + S[q]; P[q] = P[q] * Pm; }
            float Pm2 = __shfl(P[q], lm32), Sm2 = __shfl(S[q], lm32);
            if (grp >= 2) { S[q] = P[q] * Sm2 + S[q]; P[q] = P[q] * Pm2; }
        }
        if (grp == 3) {                       // chunk totals
            cfS[p][g][c0]      = make_float2(P[0], S[0]);
            cfS[p][g][c0 + 16] = make_float2(P[1], S[1]);
        }
        __syncthreads();                                              // B2

        // ---- COMB1: per-lane carry chain for channel (lane&31) ----
        const int chc = lane & 31;
        float cy = s1s[p][chc];
#pragma unroll
        for (int ch = 0; ch < NG; ++ch) {
            const float2 ax = cfS[p][ch][chc];
            const float t = ax.x * cy + ax.y;
            cy = (ch < g) ? t : cy;
        }
        if (g == NG - 1 && lane < 32) {
            const float2 aL = cfS[p][NG - 1][chc];
            s1s[p ^ 1][chc] = aL.x * cy + aL.y;
        }
        const float cyq0 = __shfl(cy, c0);
        const float cyq1 = __shfl(cy, c0 + 16);
        float gin[2];
#pragma unroll
        for (int q = 0; q < 2; ++q) {
            float Pe = __shfl(P[q], lm16), Se = __shfl(S[q], lm16);
            if (grp == 0) { Pe = 1.f; Se = 0.f; }
            gin[q] = Se + Pe * (q ? cyq1 : cyq0);
        }

        // ---- C1: fixup + residual gate; pack h1 rows to f16 LDS ----
#pragma unroll
        for (int q = 0; q < 2; ++q)
#pragma unroll
            for (int j = 0; j < 4; ++j) {
                const float st = pl[q][j] + pA[q][j] * gin[q];
                h1v[q][j] = vh0[q][j] + st * gt[q][j];
            }
#pragma unroll
        for (int j = 0; j < 4; ++j) {
            const float p0 = __shfl_xor(h1v[0][j], 1);
            const float p1 = __shfl_xor(h1v[1][j], 1);
            unsigned int w;
            if (lane & 1) {
                const pk16 pk = __builtin_amdgcn_cvt_pkrtz(p1, h1v[1][j]);
                w = __builtin_bit_cast(unsigned int, pk);
            } else {
                const pk16 pk = __builtin_amdgcn_cvt_pkrtz(h1v[0][j], p0);
                w = __builtin_bit_cast(unsigned int, pk);
            }
            h1h[cb + r0 + j][(c0 >> 1) + ((lane & 1) ? 8 : 0)] = w;
        }
        if (it == NT - 1 && g == NG - 1 && grp == 3) {
            hlast[c0]      = h1v[0][3];
            hlast[c0 + 16] = h1v[1][3];
        }
        // no barrier: C1 writes and D2 reads are within the same wave

        // ---- D2: zd2 via MFMA (A = h1 rows from LDS, K=32); scan in regs ----
        const uint4 aw2 = *reinterpret_cast<const uint4*>(&h1h[cb + c0][grp * 4]);
        const f16x8 a2 = __builtin_bit_cast(f16x8, aw2);
        float P2[2], S2[2];
#pragma unroll
        for (int q = 0; q < 2; ++q) {
            f32x4 cin;
            cin[0] = cin[1] = cin[2] = cin[3] = bd2c[q];
            const f32x4 vd2 = __builtin_amdgcn_mfma_f32_16x16x32_f16(a2, bwd2[q], cin, 0, 0, 0);
            float sp = 1.f, sl = 0.f;
#pragma unroll
            for (int j = 0; j < 4; ++j) {
                const float delta = softplus_n(vd2[j]);
                const float ab    = fexp2(delta * nA2[q]);
                sl = ab * sl + delta * h1v[q][j];   // xin uses exact f32 h1 (same slot!)
                sp *= ab;
            }
            P2[q] = sp; S2[q] = sl;
        }
#pragma unroll
        for (int q = 0; q < 2; ++q) {
            float Pm = __shfl(P2[q], lm16), Sm = __shfl(S2[q], lm16);
            if (grp >= 1) { S2[q] = P2[q] * Sm + S2[q]; P2[q] = P2[q] * Pm; }
            float Pm2 = __shfl(P2[q], lm32), Sm2 = __shfl(S2[q], lm32);
            if (grp >= 2) { S2[q] = P2[q] * Sm2 + S2[q]; P2[q] = P2[q] * Pm2; }
        }
        if (grp == 3) {
            cf2S[p][g][c0]      = make_float2(P2[0], S2[0]);
            cf2S[p][g][c0 + 16] = make_float2(P2[1], S2[1]);
        }
        if (it + 1 < NT) {      // commit prefetched x tile to the other parity
            const pk16 pk = __builtin_amdgcn_cvt_pkrtz(xnext.x, xnext.y);
            xs16[p ^ 1][xrow][xdc] = __builtin_bit_cast(unsigned int, pk);
        }
        __syncthreads();                                              // B4

        // ---- COMB2: carry only (wave0 lanes<32; cf2S parity keeps it race-free) ----
        if (tid < 32) {
            float cy2 = s2v;
#pragma unroll
            for (int ch = 0; ch < NG; ++ch) {
                const float2 ax = cf2S[p][ch][tid];
                cy2 = ax.x * cy2 + ax.y;
            }
            s2v = cy2;
        }
    }
    __syncthreads();

    // ---- head: gate2 on last token, residual, LN, GELU MLP -> scalar ----
    if (tid < HH) {
        float zg = bg[HH + tid];
#pragma unroll
        for (int k = 0; k < HH; ++k) zg += hlast[k] * Wg[HH * HH + k * HH + tid];
        const float gt2 = sigmoid_n(zg);
        const float h2  = hlast[tid] + s2v * gt2;

        float sum = h2;
#pragma unroll
        for (int m = 1; m < HH; m <<= 1) sum += __shfl_xor(sum, m);
        const float mu = sum * (1.0f / HH);
        const float d  = h2 - mu;
        float vs = d * d;
#pragma unroll
        for (int m = 1; m < HH; m <<= 1) vs += __shfl_xor(vs, m);
        const float rstd = rsqrtf(vs * (1.0f / HH) + 1e-5f);
        const float hn   = d * rstd * gmma[tid] + beta[tid];

        float z = b1[tid];
#pragma unroll
        for (int k = 0; k < HH; ++k) z += __shfl(hn, k) * W1[k * HH + tid];
        // gelu tanh-approx; tanh(t) = 1 - 2/(1+2^(2t*log2e))
        const float u  = 2.0f * L2E * 0.7978845608028654f * (z + 0.044715f * z * z * z);
        const float e  = fexp2(u);
        const float th = 1.f - 2.f * frcp(1.f + e);
        const float ge = 0.5f * z * (1.0f + th);
        float v = ge * W2[tid];
#pragma unroll
        for (int m = 1; m < HH; m <<= 1) v += __shfl_xor(v, m);
        if (tid == 0) out[b] = v + b2[0];
    }
}

extern "C" void kernel_launch(void* const* d_in, const int* in_sizes, int n_in,
                              void* d_out, int out_size, void* d_ws, size_t ws_size,
                              hipStream_t stream) {
    const float* x    = (const float*)d_in[0];
    const float* Wemb = (const float*)d_in[1];
    const float* bemb = (const float*)d_in[2];
    const float* Wd   = (const float*)d_in[3];
    const float* bd   = (const float*)d_in[4];
    const float* Alog = (const float*)d_in[5];
    const float* Wg   = (const float*)d_in[6];
    const float* bg   = (const float*)d_in[7];
    const float* gmma = (const float*)d_in[8];
    const float* beta = (const float*)d_in[9];
    const float* W1   = (const float*)d_in[10];
    const float* b1   = (const float*)d_in[11];
    const float* W2   = (const float*)d_in[12];
    const float* b2   = (const float*)d_in[13];
    float* out = (float*)d_out;

    forecast_fused<<<dim3(BB), dim3(NTHREADS), 0, stream>>>(
        x, Wemb, bemb, Wd, bd, Alog, Wg, bg, gmma, beta, W1, b1, W2, b2, out);
}

// Round 11
// 163.789 us; speedup vs baseline: 11.6167x; 1.0197x over previous
//
#include <hip/hip_runtime.h>
#include <math.h>

#define BB 256
#define SS 4096
#define FF 8
#define HH 32
#define TT 256              // timesteps per LDS tile
#define NT (SS/TT)          // 16 tiles
#define NTHREADS 1024
#define NG 16               // chunks per tile (one wave per chunk)
#define CLR 16              // rows per chunk
#define HROW 20             // h1h row stride in dwords (80B: 16B-aligned, 2-way max)

#define L2E  1.4426950408889634f
#define LN2f 0.6931471805599453f

typedef _Float16 f16x8 __attribute__((ext_vector_type(8)));
typedef float    f32x4 __attribute__((ext_vector_type(4)));
typedef __fp16   pk16  __attribute__((ext_vector_type(2)));   // cvt_pkrtz return type

__device__ __forceinline__ float fexp2(float x){
#if __has_builtin(__builtin_amdgcn_exp2f)
    return __builtin_amdgcn_exp2f(x);
#else
    return exp2f(x);
#endif
}
__device__ __forceinline__ float flog2(float x){
#if __has_builtin(__builtin_amdgcn_logf)
    return __builtin_amdgcn_logf(x);
#else
    return log2f(x);
#endif
}
__device__ __forceinline__ float frcp(float x){
#if __has_builtin(__builtin_amdgcn_rcpf)
    return __builtin_amdgcn_rcpf(x);
#else
    return 1.0f/x;
#endif
}

// softplus(z) = max(z,0) + ln2*log2(1 + 2^(-|z|*log2e))
__device__ __forceinline__ float softplus_n(float z){
    const float t = fexp2(-fabsf(z) * L2E);
    return fmaxf(z, 0.f) + LN2f * flog2(1.f + t);
}
// sigmoid(z) = 1/(1 + 2^(-z*log2e))
__device__ __forceinline__ float sigmoid_n(float z){
    return frcp(1.f + fexp2(-z * L2E));
}

__global__ __launch_bounds__(NTHREADS)
void forecast_fused(const float* __restrict__ x,
                    const float* __restrict__ Wemb, const float* __restrict__ bemb,
                    const float* __restrict__ Wd,   const float* __restrict__ bd,
                    const float* __restrict__ Alog,
                    const float* __restrict__ Wg,   const float* __restrict__ bg,
                    const float* __restrict__ gmma, const float* __restrict__ beta,
                    const float* __restrict__ W1,   const float* __restrict__ b1,
                    const float* __restrict__ W2,   const float* __restrict__ b2,
                    float* __restrict__ out)
{
    __shared__ __align__(16) unsigned int xs16[TT][4];    // x tile f16 (wave-private)  4 KB
    __shared__ __align__(16) unsigned int h1h[TT][HROW];  // h1 f16 (wave-private)     20 KB
    __shared__ float wdpS[FF][HH];         // Wemb@Wd1 composed
    __shared__ float wgpS[FF][HH];         // Wemb@Wg1 composed
    __shared__ float bdpS[HH], bgpS[HH];   // composed biases
    __shared__ float2 cfS[2][NG][HH];      // block-1 chunk totals (A,X), parity dbuf
    __shared__ float2 cf2S[2][NG][HH];     // block-2 chunk totals (A,X), parity dbuf
    __shared__ float s1s[2][HH];           // block-1 running state (parity dbuf)
    __shared__ float hlast[HH];            // exact f32 h1 of last row (head)

    const int tid  = threadIdx.x;
    const int lane = tid & 63;
    const int g    = tid >> 6;             // chunk index == wave index
    const int c0   = lane & 15;            // MFMA D col (channel, low half)
    const int grp  = lane >> 4;            // lane group 0..3 -> rows grp*4..+3
    const int r0   = grp * 4;
    const int cb   = g * CLR;              // chunk row base (tile-local)
    const int b    = blockIdx.x;
    const int lm16 = (lane - 16) & 63, lm32 = (lane - 32) & 63;
    // wave-local x staging: lane covers row cb+(lane>>2), dword pair (lane&3)
    const int srow = cb + (lane >> 2);
    const int sdc  = lane & 3;

    // ---- one-time: compose block-1 weights through the embedding ----
    if (tid < FF * HH) {
        const int f = tid >> 5, cc = tid & 31;
        float accd = 0.f, accg = 0.f;
#pragma unroll
        for (int k = 0; k < HH; ++k) {
            const float w = Wemb[f * HH + k];
            accd += w * Wd[k * HH + cc];
            accg += w * Wg[k * HH + cc];
        }
        wdpS[f][cc] = accd;
        wgpS[f][cc] = accg;
    }
    if (tid < HH) {
        float ad = bd[tid], ag = bg[tid];
#pragma unroll
        for (int k = 0; k < HH; ++k) {
            ad += bemb[k] * Wd[k * HH + tid];
            ag += bemb[k] * Wg[k * HH + tid];
        }
        bdpS[tid] = ad; bgpS[tid] = ag;
        s1s[0][tid] = 0.f;
    }
    __syncthreads();

    // ---- B-fragments (k = (lane>>4)*8 + j; same chosen k-order for A and B)
    //      and per-channel constants for this lane's two columns ----
    f16x8 bh0[2], bzd[2], bzg[2], bwd2[2];
    float bec[2], bd1p[2], bg1p[2], bd2c[2], nA1[2], nA2[2];
#pragma unroll
    for (int q = 0; q < 2; ++q) {
        const int cq = c0 + 16 * q;
#pragma unroll
        for (int j = 0; j < 8; ++j) {
            // D1 operands: K=8 padded to 32 -> only k-block 0 (lanes<16) is real
            bh0[q][j] = (lane < 16) ? (_Float16)Wemb[j * HH + cq] : (_Float16)0.f;
            bzd[q][j] = (lane < 16) ? (_Float16)wdpS[j][cq]       : (_Float16)0.f;
            bzg[q][j] = (lane < 16) ? (_Float16)wgpS[j][cq]       : (_Float16)0.f;
            // D2 operand: full K=32
            bwd2[q][j] = (_Float16)Wd[HH * HH + (grp * 8 + j) * HH + cq];
        }
        bec[q]  = bemb[cq];
        bd1p[q] = bdpS[cq]; bg1p[q] = bgpS[cq];
        bd2c[q] = bd[HH + cq];
        nA1[q] = -expf(Alog[cq]) * L2E;
        nA2[q] = -expf(Alog[HH + cq]) * L2E;
    }

    float s2v = 0.f;                       // block-2 running carry (wave0 lanes<32)

    // ---- prologue: each wave stages its own rows of tile 0 ----
    {
        const float2 xv = *reinterpret_cast<const float2*>(
            x + ((size_t)b * SS + srow) * FF + sdc * 2);
        const pk16 pk = __builtin_amdgcn_cvt_pkrtz(xv.x, xv.y);
        xs16[srow][sdc] = __builtin_bit_cast(unsigned int, pk);
        // intra-wave DS FIFO: D1's read below is ordered after this write
    }

    for (int it = 0; it < NT; ++it) {
        const int p = it & 1;

        // ---- prefetch next x tile rows into registers (wave-local) ----
        float2 xnext = make_float2(0.f, 0.f);
        if (it + 1 < NT)
            xnext = *reinterpret_cast<const float2*>(
                x + ((size_t)b * SS + (it + 1) * TT + srow) * FF + sdc * 2);

        // ---- D1: h0/zd1/zg1 via MFMA (A = own x rows, K=8 padded) ----
        uint4 aw = make_uint4(0u, 0u, 0u, 0u);
        if (lane < 16) aw = *reinterpret_cast<const uint4*>(&xs16[cb + c0][0]);
        const f16x8 a1 = __builtin_bit_cast(f16x8, aw);
        f32x4 vh0[2], vzd[2], vzg[2];
#pragma unroll
        for (int q = 0; q < 2; ++q) {
            f32x4 cin;
            cin[0] = cin[1] = cin[2] = cin[3] = bec[q];
            vh0[q] = __builtin_amdgcn_mfma_f32_16x16x32_f16(a1, bh0[q], cin, 0, 0, 0);
            cin[0] = cin[1] = cin[2] = cin[3] = bd1p[q];
            vzd[q] = __builtin_amdgcn_mfma_f32_16x16x32_f16(a1, bzd[q], cin, 0, 0, 0);
            cin[0] = cin[1] = cin[2] = cin[3] = bg1p[q];
            vzg[q] = __builtin_amdgcn_mfma_f32_16x16x32_f16(a1, bzg[q], cin, 0, 0, 0);
        }

        // ---- pointwise + group-local (4-row) scan, in registers ----
        float pA[2][4], pl[2][4], gt[2][4], h1v[2][4];
#pragma unroll
        for (int q = 0; q < 2; ++q) {
            float sp = 1.f, sl = 0.f;
#pragma unroll
            for (int j = 0; j < 4; ++j) {
                const float delta = softplus_n(vzd[q][j]);
                const float ab    = fexp2(delta * nA1[q]);
                sl = ab * sl + delta * vh0[q][j];
                sp *= ab;
                pA[q][j] = sp; pl[q][j] = sl;
                gt[q][j] = sigmoid_n(vzg[q][j]);
            }
        }
        // Kogge-Stone inclusive scan of (A,X) over the 4 lane-groups
        float P[2], S[2];
        P[0] = pA[0][3]; S[0] = pl[0][3];
        P[1] = pA[1][3]; S[1] = pl[1][3];
#pragma unroll
        for (int q = 0; q < 2; ++q) {
            float Pm = __shfl(P[q], lm16), Sm = __shfl(S[q], lm16);
            if (grp >= 1) { S[q] = P[q] * Sm + S[q]; P[q] = P[q] * Pm; }
            float Pm2 = __shfl(P[q], lm32), Sm2 = __shfl(S[q], lm32);
            if (grp >= 2) { S[q] = P[q] * Sm2 + S[q]; P[q] = P[q] * Pm2; }
        }
        if (grp == 3) {                       // chunk totals
            cfS[p][g][c0]      = make_float2(P[0], S[0]);
            cfS[p][g][c0 + 16] = make_float2(P[1], S[1]);
        }
        __syncthreads();                      // THE barrier (1 per tile)

        // ---- COMB1: per-lane carry chain for channel (lane&31) ----
        const int chc = lane & 31;
        float cy = s1s[p][chc];
#pragma unroll
        for (int ch = 0; ch < NG; ++ch) {
            const float2 ax = cfS[p][ch][chc];
            const float t = ax.x * cy + ax.y;
            cy = (ch < g) ? t : cy;
        }
        if (g == NG - 1 && lane < 32) {
            const float2 aL = cfS[p][NG - 1][chc];
            s1s[p ^ 1][chc] = aL.x * cy + aL.y;
        }
        const float cyq0 = __shfl(cy, c0);
        const float cyq1 = __shfl(cy, c0 + 16);
        float gin[2];
#pragma unroll
        for (int q = 0; q < 2; ++q) {
            float Pe = __shfl(P[q], lm16), Se = __shfl(S[q], lm16);
            if (grp == 0) { Pe = 1.f; Se = 0.f; }
            gin[q] = Se + Pe * (q ? cyq1 : cyq0);
        }

        // ---- C1: fixup + residual gate; pack h1 rows to f16 LDS (own rows) ----
#pragma unroll
        for (int q = 0; q < 2; ++q)
#pragma unroll
            for (int j = 0; j < 4; ++j) {
                const float st = pl[q][j] + pA[q][j] * gin[q];
                h1v[q][j] = vh0[q][j] + st * gt[q][j];
            }
#pragma unroll
        for (int j = 0; j < 4; ++j) {
            const float p0 = __shfl_xor(h1v[0][j], 1);
            const float p1 = __shfl_xor(h1v[1][j], 1);
            unsigned int w;
            if (lane & 1) {
                const pk16 pk = __builtin_amdgcn_cvt_pkrtz(p1, h1v[1][j]);
                w = __builtin_bit_cast(unsigned int, pk);
            } else {
                const pk16 pk = __builtin_amdgcn_cvt_pkrtz(h1v[0][j], p0);
                w = __builtin_bit_cast(unsigned int, pk);
            }
            h1h[cb + r0 + j][(c0 >> 1) + ((lane & 1) ? 8 : 0)] = w;
        }
        if (it == NT - 1 && g == NG - 1 && grp == 3) {
            hlast[c0]      = h1v[0][3];
            hlast[c0 + 16] = h1v[1][3];
        }

        // ---- D2: zd2 via MFMA (A = own h1 rows, K=32); scan in regs ----
        const uint4 aw2 = *reinterpret_cast<const uint4*>(&h1h[cb + c0][grp * 4]);
        const f16x8 a2 = __builtin_bit_cast(f16x8, aw2);
        float P2[2], S2[2];
#pragma unroll
        for (int q = 0; q < 2; ++q) {
            f32x4 cin;
            cin[0] = cin[1] = cin[2] = cin[3] = bd2c[q];
            const f32x4 vd2 = __builtin_amdgcn_mfma_f32_16x16x32_f16(a2, bwd2[q], cin, 0, 0, 0);
            float sp = 1.f, sl = 0.f;
#pragma unroll
            for (int j = 0; j < 4; ++j) {
                const float delta = softplus_n(vd2[j]);
                const float ab    = fexp2(delta * nA2[q]);
                sl = ab * sl + delta * h1v[q][j];   // xin uses exact f32 h1
                sp *= ab;
            }
            P2[q] = sp; S2[q] = sl;
        }
#pragma unroll
        for (int q = 0; q < 2; ++q) {
            float Pm = __shfl(P2[q], lm16), Sm = __shfl(S2[q], lm16);
            if (grp >= 1) { S2[q] = P2[q] * Sm + S2[q]; P2[q] = P2[q] * Pm; }
            float Pm2 = __shfl(P2[q], lm32), Sm2 = __shfl(S2[q], lm32);
            if (grp >= 2) { S2[q] = P2[q] * Sm2 + S2[q]; P2[q] = P2[q] * Pm2; }
        }
        if (grp == 3) {
            cf2S[p][g][c0]      = make_float2(P2[0], S2[0]);
            cf2S[p][g][c0 + 16] = make_float2(P2[1], S2[1]);
        }

        // ---- COMB2 for tile it-1 (pipelined; cf2S[p^1] is barrier-separated) ----
        if (it > 0 && tid < 32) {
            float cy2 = s2v;
#pragma unroll
            for (int ch = 0; ch < NG; ++ch) {
                const float2 ax = cf2S[p ^ 1][ch][tid];
                cy2 = ax.x * cy2 + ax.y;
            }
            s2v = cy2;
        }

        // ---- commit prefetched x rows (wave-private region) ----
        if (it + 1 < NT) {
            const pk16 pk = __builtin_amdgcn_cvt_pkrtz(xnext.x, xnext.y);
            xs16[srow][sdc] = __builtin_bit_cast(unsigned int, pk);
        }
    }
    __syncthreads();

    // ---- final COMB2 (tile NT-1) + head ----
    if (tid < HH) {
        {
            float cy2 = s2v;
#pragma unroll
            for (int ch = 0; ch < NG; ++ch) {
                const float2 ax = cf2S[(NT - 1) & 1][ch][tid];
                cy2 = ax.x * cy2 + ax.y;
            }
            s2v = cy2;
        }
        float zg = bg[HH + tid];
#pragma unroll
        for (int k = 0; k < HH; ++k) zg += hlast[k] * Wg[HH * HH + k * HH + tid];
        const float gt2 = sigmoid_n(zg);
        const float h2  = hlast[tid] + s2v * gt2;

        float sum = h2;
#pragma unroll
        for (int m = 1; m < HH; m <<= 1) sum += __shfl_xor(sum, m);
        const float mu = sum * (1.0f / HH);
        const float d  = h2 - mu;
        float vs = d * d;
#pragma unroll
        for (int m = 1; m < HH; m <<= 1) vs += __shfl_xor(vs, m);
        const float rstd = rsqrtf(vs * (1.0f / HH) + 1e-5f);
        const float hn   = d * rstd * gmma[tid] + beta[tid];

        float z = b1[tid];
#pragma unroll
        for (int k = 0; k < HH; ++k) z += __shfl(hn, k) * W1[k * HH + tid];
        // gelu tanh-approx; tanh(t) = 1 - 2/(1+2^(2t*log2e))
        const float u  = 2.0f * L2E * 0.7978845608028654f * (z + 0.044715f * z * z * z);
        const float e  = fexp2(u);
        const float th = 1.f - 2.f * frcp(1.f + e);
        const float ge = 0.5f * z * (1.0f + th);
        float v = ge * W2[tid];
#pragma unroll
        for (int m = 1; m < HH; m <<= 1) v += __shfl_xor(v, m);
        if (tid == 0) out[b] = v + b2[0];
    }
}

extern "C" void kernel_launch(void* const* d_in, const int* in_sizes, int n_in,
                              void* d_out, int out_size, void* d_ws, size_t ws_size,
                              hipStream_t stream) {
    const float* x    = (const float*)d_in[0];
    const float* Wemb = (const float*)d_in[1];
    const float* bemb = (const float*)d_in[2];
    const float* Wd   = (const float*)d_in[3];
    const float* bd   = (const float*)d_in[4];
    const float* Alog = (const float*)d_in[5];
    const float* Wg   = (const float*)d_in[6];
    const float* bg   = (const float*)d_in[7];
    const float* gmma = (const float*)d_in[8];
    const float* beta = (const float*)d_in[9];
    const float* W1   = (const float*)d_in[10];
    const float* b1   = (const float*)d_in[11];
    const float* W2   = (const float*)d_in[12];
    const float* b2   = (const float*)d_in[13];
    float* out = (float*)d_out;

    forecast_fused<<<dim3(BB), dim3(NTHREADS), 0, stream>>>(
        x, Wemb, bemb, Wd, bd, Alog, Wg, bg, gmma, beta, W1, b1, W2, b2, out);
}